// Round 1
// baseline (2384.119 us; speedup 1.0000x reference)
//
#include <hip/hip_runtime.h>
#include <cstddef>

#define HID 128
#define NGRAPH 256
#define KIT 5
#define BCAP 64

constexpr int BM = 64;
constexpr int BKK = 64;

// ---------------- bucket build (CSR-lite, capacity BCAP per node) ----------------
__global__ __launch_bounds__(256) void k_bucket(const int* __restrict__ esrc,
                                                const int* __restrict__ edst,
                                                int* __restrict__ cnt,
                                                int* __restrict__ bucket, int E) {
    int e = blockIdx.x * 256 + threadIdx.x;
    if (e >= E) return;
    int d = edst[e];
    int slot = atomicAdd(cnt + d, 1);
    if (slot < BCAP) bucket[(size_t)d * BCAP + slot] = esrc[e];
}

// ---------------- neighbor-sum gather: agg = h + sum_{src in nbr(n)} h[src] -----
__global__ __launch_bounds__(128) void k_gather(const float* __restrict__ h,
                                                const int* __restrict__ cnt,
                                                const int* __restrict__ bucket,
                                                float* __restrict__ agg, int N) {
    int n = blockIdx.x;
    int c = threadIdx.x;
    __shared__ int sb[BCAP];
    int deg = cnt[n]; if (deg > BCAP) deg = BCAP;
    if (c < deg) sb[c] = bucket[(size_t)n * BCAP + c];
    __syncthreads();
    float acc = h[(size_t)n * HID + c];   // (1+eps)*h with eps=0
    for (int j = 0; j < deg; ++j)
        acc += h[(size_t)sb[j] * HID + c];
    agg[(size_t)n * HID + c] = acc;
}

// ---------------- fp32 GEMM  Out[M,128] = f(A)[M,128] @ W[128,128] + bias -------
// FUSE_IN: A' = relu(A*scale_in[k] + shift_in[k])  (applies previous BN+ReLU)
// STATS:   accumulate per-column sum/sumsq of (Out) into stats[0..127]/[128..255]
template<bool FUSE_IN, bool STATS>
__global__ __launch_bounds__(256) void k_gemm(const float* __restrict__ A,
                                              const float* __restrict__ W,
                                              const float* __restrict__ bias,
                                              const float* __restrict__ ssin,
                                              float* __restrict__ Out,
                                              float* __restrict__ stats, int M) {
    __shared__ float As[BM][BKK + 1];
    __shared__ float Bs[BKK][HID];
    __shared__ float csum[HID], csq[HID];

    const int t = threadIdx.x;
    const int tn = t & 15;   // 16 col-groups
    const int tm = t >> 4;   // 16 row-groups
    const int r0 = blockIdx.x * BM;

    float acc[4][8];
#pragma unroll
    for (int i = 0; i < 4; ++i)
#pragma unroll
        for (int j = 0; j < 8; ++j) acc[i][j] = 0.f;

    for (int s = 0; s < HID; s += BKK) {
        // A tile: 64 rows x 64 k  (1024 float4, 4 per thread)
#pragma unroll
        for (int p = 0; p < 4; ++p) {
            int idx = t + p * 256;
            int ar = idx >> 4;
            int ac = idx & 15;
            int gr = r0 + ar;
            float4 v = make_float4(0.f, 0.f, 0.f, 0.f);
            if (gr < M) v = reinterpret_cast<const float4*>(A + (size_t)gr * HID + s)[ac];
            if constexpr (FUSE_IN) {
                int k = s + ac * 4;
                const float4 sc = *reinterpret_cast<const float4*>(ssin + k);
                const float4 sh = *reinterpret_cast<const float4*>(ssin + HID + k);
                v.x = fmaxf(fmaf(v.x, sc.x, sh.x), 0.f);
                v.y = fmaxf(fmaf(v.y, sc.y, sh.y), 0.f);
                v.z = fmaxf(fmaf(v.z, sc.z, sh.z), 0.f);
                v.w = fmaxf(fmaf(v.w, sc.w, sh.w), 0.f);
            }
            As[ar][ac * 4 + 0] = v.x; As[ar][ac * 4 + 1] = v.y;
            As[ar][ac * 4 + 2] = v.z; As[ar][ac * 4 + 3] = v.w;
        }
        // B tile: 64 k x 128 cols (2048 float4, 8 per thread)
#pragma unroll
        for (int p = 0; p < 8; ++p) {
            int idx = t + p * 256;
            int br = idx >> 5;
            int bc = idx & 31;
            float4 v = reinterpret_cast<const float4*>(W + (size_t)(s + br) * HID)[bc];
            *reinterpret_cast<float4*>(&Bs[br][bc * 4]) = v;
        }
        __syncthreads();
#pragma unroll
        for (int kk = 0; kk < BKK; ++kk) {
            float av[4];
#pragma unroll
            for (int i = 0; i < 4; ++i) av[i] = As[tm * 4 + i][kk];
            float4 b0 = *reinterpret_cast<const float4*>(&Bs[kk][tn * 4]);
            float4 b1 = *reinterpret_cast<const float4*>(&Bs[kk][64 + tn * 4]);
            float bv[8] = {b0.x, b0.y, b0.z, b0.w, b1.x, b1.y, b1.z, b1.w};
#pragma unroll
            for (int i = 0; i < 4; ++i)
#pragma unroll
                for (int j = 0; j < 8; ++j) acc[i][j] = fmaf(av[i], bv[j], acc[i][j]);
        }
        __syncthreads();
    }

    const float4 bia0 = *reinterpret_cast<const float4*>(bias + tn * 4);
    const float4 bia1 = *reinterpret_cast<const float4*>(bias + 64 + tn * 4);
    float colsum[8], colsq[8];
#pragma unroll
    for (int j = 0; j < 8; ++j) { colsum[j] = 0.f; colsq[j] = 0.f; }

#pragma unroll
    for (int i = 0; i < 4; ++i) {
        int gr = r0 + tm * 4 + i;
        if (gr < M) {
            float o[8];
            o[0] = acc[i][0] + bia0.x; o[1] = acc[i][1] + bia0.y;
            o[2] = acc[i][2] + bia0.z; o[3] = acc[i][3] + bia0.w;
            o[4] = acc[i][4] + bia1.x; o[5] = acc[i][5] + bia1.y;
            o[6] = acc[i][6] + bia1.z; o[7] = acc[i][7] + bia1.w;
            *reinterpret_cast<float4*>(Out + (size_t)gr * HID + tn * 4)      = make_float4(o[0], o[1], o[2], o[3]);
            *reinterpret_cast<float4*>(Out + (size_t)gr * HID + 64 + tn * 4) = make_float4(o[4], o[5], o[6], o[7]);
            if constexpr (STATS) {
#pragma unroll
                for (int j = 0; j < 8; ++j) { colsum[j] += o[j]; colsq[j] += o[j] * o[j]; }
            }
        }
    }
    if constexpr (STATS) {
        if (t < HID) { csum[t] = 0.f; csq[t] = 0.f; }
        __syncthreads();
#pragma unroll
        for (int j = 0; j < 8; ++j) {
            int col = (j < 4) ? (tn * 4 + j) : (64 + tn * 4 + (j - 4));
            atomicAdd(&csum[col], colsum[j]);
            atomicAdd(&csq[col], colsq[j]);
        }
        __syncthreads();
        if (t < HID) {
            atomicAdd(stats + t, csum[t]);
            atomicAdd(stats + HID + t, csq[t]);
        }
    }
}

// ---------------- finalize BN: scale = g*rsqrt(var+eps), shift = be - mean*scale --
__global__ __launch_bounds__(HID) void k_fin(const float* __restrict__ st,
                                             const float* __restrict__ g,
                                             const float* __restrict__ be,
                                             float* __restrict__ ss, int M) {
    int c = threadIdx.x;
    float invM = 1.f / (float)M;
    float m = st[c] * invM;
    float v = fmaxf(st[HID + c] * invM - m * m, 0.f);
    float sc = rsqrtf(v + 1e-5f) * g[c];
    ss[c] = sc;
    ss[HID + c] = fmaf(-m, sc, be[c]);
}

// ---------------- elementwise BN+ReLU: h = relu(p*scale + shift) ----------------
__global__ __launch_bounds__(256) void k_bnrelu(const float* __restrict__ p,
                                                const float* __restrict__ ss,
                                                float* __restrict__ h, int n4) {
    int i = blockIdx.x * 256 + threadIdx.x;
    if (i >= n4) return;
    int c4 = i & 31;
    float4 v = reinterpret_cast<const float4*>(p)[i];
    float4 sc = reinterpret_cast<const float4*>(ss)[c4];
    float4 sh = reinterpret_cast<const float4*>(ss)[32 + c4];
    v.x = fmaxf(fmaf(v.x, sc.x, sh.x), 0.f);
    v.y = fmaxf(fmaf(v.y, sc.y, sh.y), 0.f);
    v.z = fmaxf(fmaf(v.z, sc.z, sh.z), 0.f);
    v.w = fmaxf(fmaf(v.w, sc.w, sh.w), 0.f);
    reinterpret_cast<float4*>(h)[i] = v;
}

// ---------------- per-graph add-pool (batch_index sorted -> no atomics) ---------
__global__ __launch_bounds__(HID) void k_pool(const float* __restrict__ h,
                                              const int* __restrict__ batch,
                                              int N, float* __restrict__ feats, int it) {
    int g = blockIdx.x;
    int a = 0, b = N;
    while (a < b) { int m = (a + b) >> 1; if (batch[m] < g) a = m + 1; else b = m; }
    int lo = a;
    b = N;
    while (a < b) { int m = (a + b) >> 1; if (batch[m] < g + 1) a = m + 1; else b = m; }
    int hi = a;
    int c = threadIdx.x;
    float acc = 0.f;
    for (int r = lo; r < hi; ++r) acc += h[(size_t)r * HID + c];
    feats[(size_t)g * (KIT * HID) + it * HID + c] = acc;
}

// ---------------- head layer 1: z1 = relu(feats @ Wh1 + bh1)  [256,640] ---------
__global__ __launch_bounds__(KIT * HID) void k_head1(const float* __restrict__ feats,
                                                     const float* __restrict__ Wh1,
                                                     const float* __restrict__ bh1,
                                                     float* __restrict__ z1) {
    __shared__ float fr[KIT * HID];
    int r = blockIdx.x;
    int c = threadIdx.x;
    fr[c] = feats[r * (KIT * HID) + c];
    __syncthreads();
    float acc = bh1[c];
    for (int k = 0; k < KIT * HID; ++k) acc = fmaf(fr[k], Wh1[k * (KIT * HID) + c], acc);
    z1[r * (KIT * HID) + c] = fmaxf(acc, 0.f);
}

// ---------------- head layer 2: out = z1 @ Wh2 + bh2  [256,10] ------------------
__global__ __launch_bounds__(64) void k_head2(const float* __restrict__ z1,
                                              const float* __restrict__ Wh2,
                                              const float* __restrict__ bh2,
                                              float* __restrict__ out, int total) {
    int gid = blockIdx.x * 64 + threadIdx.x;
    if (gid >= total) return;
    int r = gid / 10, c = gid % 10;
    float acc = bh2[c];
    for (int k = 0; k < KIT * HID; ++k) acc = fmaf(z1[r * (KIT * HID) + k], Wh2[k * 10 + c], acc);
    out[gid] = acc;
}

extern "C" void kernel_launch(void* const* d_in, const int* in_sizes, int n_in,
                              void* d_out, int out_size, void* d_ws, size_t ws_size,
                              hipStream_t stream) {
    const float* X   = (const float*)d_in[0];
    const float* W1  = (const float*)d_in[1];
    const float* b1  = (const float*)d_in[2];
    const float* g1  = (const float*)d_in[3];
    const float* be1 = (const float*)d_in[4];
    const float* W2  = (const float*)d_in[5];
    const float* b2  = (const float*)d_in[6];
    const float* g2  = (const float*)d_in[7];
    const float* be2 = (const float*)d_in[8];
    const float* Wh1 = (const float*)d_in[9];
    const float* bh1 = (const float*)d_in[10];
    const float* Wh2 = (const float*)d_in[11];
    const float* bh2 = (const float*)d_in[12];
    const int* esrc  = (const int*)d_in[13];
    const int* edst  = (const int*)d_in[14];
    const int* batch = (const int*)d_in[15];
    float* out = (float*)d_out;

    const int N = in_sizes[0] / HID;
    const int E = in_sizes[13];

    char* w = (char*)d_ws;
    size_t off = 0;
    auto alloc = [&](size_t bytes) {
        void* p = w + off;
        off += (bytes + 255) & ~(size_t)255;
        return p;
    };
    float* buf_h  = (float*)alloc((size_t)N * HID * 4);
    float* buf_a  = (float*)alloc((size_t)N * HID * 4);
    float* buf_p  = (float*)alloc((size_t)N * HID * 4);
    float* feats  = (float*)alloc((size_t)NGRAPH * KIT * HID * 4);
    float* z1     = (float*)alloc((size_t)NGRAPH * KIT * HID * 4);
    float* stats  = (float*)alloc((size_t)2 * KIT * 2 * HID * 4);
    float* ssbuf  = (float*)alloc((size_t)2 * KIT * 2 * HID * 4);
    int*   cnt    = (int*)alloc((size_t)N * 4);
    int*   bucket = (int*)alloc((size_t)N * BCAP * 4);

    hipMemsetAsync(cnt, 0, (size_t)N * 4, stream);
    hipMemsetAsync(stats, 0, (size_t)2 * KIT * 2 * HID * 4, stream);

    k_bucket<<<(E + 255) / 256, 256, 0, stream>>>(esrc, edst, cnt, bucket, E);

    const int gemmGrid = (N + BM - 1) / BM;
    for (int i = 0; i < KIT; ++i) {
        const float* hin = (i == 0) ? X : buf_h;
        float* st1 = stats + (size_t)(2 * i) * 256;
        float* st2 = stats + (size_t)(2 * i + 1) * 256;
        float* ss1 = ssbuf + (size_t)(2 * i) * 256;
        float* ss2 = ssbuf + (size_t)(2 * i + 1) * 256;

        k_gather<<<N, HID, 0, stream>>>(hin, cnt, bucket, buf_a, N);
        k_gemm<false, true><<<gemmGrid, 256, 0, stream>>>(
            buf_a, W1 + (size_t)i * HID * HID, b1 + i * HID, nullptr, buf_p, st1, N);
        k_fin<<<1, HID, 0, stream>>>(st1, g1 + i * HID, be1 + i * HID, ss1, N);
        k_gemm<true, true><<<gemmGrid, 256, 0, stream>>>(
            buf_p, W2 + (size_t)i * HID * HID, b2 + i * HID, ss1, buf_a, st2, N);
        k_fin<<<1, HID, 0, stream>>>(st2, g2 + i * HID, be2 + i * HID, ss2, N);

        int n4 = N * (HID / 4);
        k_bnrelu<<<(n4 + 255) / 256, 256, 0, stream>>>(buf_a, ss2, buf_h, n4);
        k_pool<<<NGRAPH, HID, 0, stream>>>(buf_h, batch, N, feats, i);
    }
    k_head1<<<NGRAPH, KIT * HID, 0, stream>>>(feats, Wh1, bh1, z1);
    k_head2<<<(NGRAPH * 10 + 63) / 64, 64, 0, stream>>>(z1, Wh2, bh2, out, NGRAPH * 10);
}

// Round 2
// 1976.820 us; speedup vs baseline: 1.2060x; 1.2060x over previous
//
#include <hip/hip_runtime.h>
#include <cstddef>

#define HID 128
#define NGRAPH 256
#define KIT 5
#define BCAP 64

typedef __attribute__((ext_vector_type(8))) short  short8v;
typedef __attribute__((ext_vector_type(8))) unsigned short ushort8v;
typedef __attribute__((ext_vector_type(4))) float  float4v;

__device__ __forceinline__ unsigned short f2b(float f) {
    unsigned int u = __float_as_uint(f);
    u = (u + 0x7FFFu + ((u >> 16) & 1u)) >> 16;
    return (unsigned short)u;
}
__device__ __forceinline__ float b2f(unsigned short b) {
    return __uint_as_float(((unsigned int)b) << 16);
}

// ---------------- bucket build (CSR-lite, capacity BCAP per node) ----------------
__global__ __launch_bounds__(256) void k_bucket(const int* __restrict__ esrc,
                                                const int* __restrict__ edst,
                                                int* __restrict__ cnt,
                                                int* __restrict__ bucket, int E) {
    int e = blockIdx.x * 256 + threadIdx.x;
    if (e >= E) return;
    int d = edst[e];
    int slot = atomicAdd(cnt + d, 1);
    if (slot < BCAP) bucket[(size_t)d * BCAP + slot] = esrc[e];
}

// -------- gather: agg[n] = f(h[n]) + sum f(h[src]),  f = BN+ReLU (or identity) ---
// FIRST: input is fp32 X, identity transform. else: input bf16 p2, f = relu(v*sc+sh).
// One 64-lane wave per node; lane handles 2 columns. Output bf16.
template<bool FIRST>
__global__ __launch_bounds__(256) void k_gather2(const void* __restrict__ hin,
                                                 const float* __restrict__ ss,
                                                 const int* __restrict__ cnt,
                                                 const int* __restrict__ bucket,
                                                 unsigned short* __restrict__ agg, int N) {
    const int wid  = threadIdx.x >> 6;
    const int lane = threadIdx.x & 63;
    const int n = blockIdx.x * 4 + wid;
    if (n >= N) return;
    const int c = lane * 2;

    int deg = cnt[n]; if (deg > BCAP) deg = BCAP;
    int sb = (lane < deg) ? bucket[(size_t)n * BCAP + lane] : 0;

    float sc0 = 1.f, sc1 = 1.f, sh0 = 0.f, sh1 = 0.f;
    if constexpr (!FIRST) {
        sc0 = ss[c]; sc1 = ss[c + 1];
        sh0 = ss[HID + c]; sh1 = ss[HID + c + 1];
    }

    float a0, a1;
    if constexpr (FIRST) {
        const float2 v = *reinterpret_cast<const float2*>((const float*)hin + (size_t)n * HID + c);
        a0 = v.x; a1 = v.y;
    } else {
        const ushort2 v = *reinterpret_cast<const ushort2*>((const unsigned short*)hin + (size_t)n * HID + c);
        a0 = fmaxf(fmaf(b2f(v.x), sc0, sh0), 0.f);
        a1 = fmaxf(fmaf(b2f(v.y), sc1, sh1), 0.f);
    }

    for (int j = 0; j < deg; ++j) {
        int src = __shfl(sb, j);
        if constexpr (FIRST) {
            const float2 v = *reinterpret_cast<const float2*>((const float*)hin + (size_t)src * HID + c);
            a0 += v.x; a1 += v.y;
        } else {
            const ushort2 v = *reinterpret_cast<const ushort2*>((const unsigned short*)hin + (size_t)src * HID + c);
            a0 += fmaxf(fmaf(b2f(v.x), sc0, sh0), 0.f);
            a1 += fmaxf(fmaf(b2f(v.y), sc1, sh1), 0.f);
        }
    }
    ushort2 o; o.x = f2b(a0); o.y = f2b(a1);
    *reinterpret_cast<ushort2*>(agg + (size_t)n * HID + c) = o;
}

// -------- bf16 MFMA GEMM: Out[M,128] = g(A)[M,128] @ W[128,128] + bias ----------
// A bf16 row-major. Wt bf16 pre-transposed: Wt[n][k]. Out bf16. Stats (sum/sumsq of
// fp32 out incl. bias) accumulated into stats[0..127]/[128..255].
// FUSE_IN: g(A) = relu(A*scale[k]+shift[k]) applied on fragment load.
template<bool FUSE_IN>
__global__ __launch_bounds__(256) void k_gemm_mfma(const unsigned short* __restrict__ A,
                                                   const unsigned short* __restrict__ Wt,
                                                   const float* __restrict__ bias,
                                                   const float* __restrict__ ssin,
                                                   unsigned short* __restrict__ Out,
                                                   float* __restrict__ stats, int M) {
    __shared__ float csum[HID], csq[HID];
    const int wave = threadIdx.x >> 6;
    const int lane = threadIdx.x & 63;
    const int lr = lane & 15;   // A row / B col / C col within 16
    const int lk = lane >> 4;   // k sub-group 0..3
    const int r0 = blockIdx.x * 64 + wave * 16;
    const int arow = r0 + lr;
    const bool rowok = arow < M;

    // A fragments for K=128 (4 k-blocks of 32)
    short8v af[4];
    const unsigned short* ap = A + (size_t)arow * HID + lk * 8;
#pragma unroll
    for (int kb = 0; kb < 4; ++kb) {
        ushort8v raw;
        if (rowok) raw = *reinterpret_cast<const ushort8v*>(ap + kb * 32);
        else       raw = (ushort8v)(unsigned short)0;
        if constexpr (FUSE_IN) {
            const int k0 = kb * 32 + lk * 8;
            const float4v sc0 = *reinterpret_cast<const float4v*>(ssin + k0);
            const float4v sc1 = *reinterpret_cast<const float4v*>(ssin + k0 + 4);
            const float4v sh0 = *reinterpret_cast<const float4v*>(ssin + HID + k0);
            const float4v sh1 = *reinterpret_cast<const float4v*>(ssin + HID + k0 + 4);
#pragma unroll
            for (int j = 0; j < 4; ++j) {
                raw[j]     = f2b(fmaxf(fmaf(b2f(raw[j]),     sc0[j], sh0[j]), 0.f));
                raw[j + 4] = f2b(fmaxf(fmaf(b2f(raw[j + 4]), sc1[j], sh1[j]), 0.f));
            }
        }
        af[kb] = *reinterpret_cast<short8v*>(&raw);
    }

    // 8 column tiles of 16
    float4v acc[8];
#pragma unroll
    for (int ct = 0; ct < 8; ++ct) {
        float4v c = {0.f, 0.f, 0.f, 0.f};
        const unsigned short* bp = Wt + (size_t)(ct * 16 + lr) * HID + lk * 8;
#pragma unroll
        for (int kb = 0; kb < 4; ++kb) {
            short8v bf = *reinterpret_cast<const short8v*>(bp + kb * 32);
            c = __builtin_amdgcn_mfma_f32_16x16x32_bf16(af[kb], bf, c, 0, 0, 0);
        }
        acc[ct] = c;
    }

    if (threadIdx.x < HID) { csum[threadIdx.x] = 0.f; csq[threadIdx.x] = 0.f; }
    __syncthreads();

#pragma unroll
    for (int ct = 0; ct < 8; ++ct) {
        const int col = ct * 16 + lr;
        const float b = bias[col];
        float s = 0.f, q = 0.f;
#pragma unroll
        for (int j = 0; j < 4; ++j) {
            const int row = r0 + lk * 4 + j;
            if (row < M) {
                const float o = acc[ct][j] + b;
                Out[(size_t)row * HID + col] = f2b(o);
                s += o; q += o * o;
            }
        }
        s += __shfl_xor(s, 16); s += __shfl_xor(s, 32);
        q += __shfl_xor(q, 16); q += __shfl_xor(q, 32);
        if (lk == 0) { atomicAdd(&csum[col], s); atomicAdd(&csq[col], q); }
    }
    __syncthreads();
    if (threadIdx.x < HID) {
        atomicAdd(stats + threadIdx.x, csum[threadIdx.x]);
        atomicAdd(stats + HID + threadIdx.x, csq[threadIdx.x]);
    }
}

// ---------------- finalize BN: scale = g*rsqrt(var+eps), shift = be - mean*scale --
__global__ __launch_bounds__(HID) void k_fin(const float* __restrict__ st,
                                             const float* __restrict__ g,
                                             const float* __restrict__ be,
                                             float* __restrict__ ss, int M) {
    int c = threadIdx.x;
    float invM = 1.f / (float)M;
    float m = st[c] * invM;
    float v = fmaxf(st[HID + c] * invM - m * m, 0.f);
    float sc = rsqrtf(v + 1e-5f) * g[c];
    ss[c] = sc;
    ss[HID + c] = fmaf(-m, sc, be[c]);
}

// -------- per-graph add-pool of relu(bn(p2)) (batch_index sorted, no atomics) ----
__global__ __launch_bounds__(HID) void k_pool2(const unsigned short* __restrict__ p2,
                                               const float* __restrict__ ss,
                                               const int* __restrict__ batch,
                                               int N, float* __restrict__ feats, int it) {
    int g = blockIdx.x;
    int a = 0, b = N;
    while (a < b) { int m = (a + b) >> 1; if (batch[m] < g) a = m + 1; else b = m; }
    int lo = a;
    b = N;
    while (a < b) { int m = (a + b) >> 1; if (batch[m] < g + 1) a = m + 1; else b = m; }
    int hi = a;
    int c = threadIdx.x;
    const float sc = ss[c], sh = ss[HID + c];
    float acc = 0.f;
    for (int r = lo; r < hi; ++r)
        acc += fmaxf(fmaf(b2f(p2[(size_t)r * HID + c]), sc, sh), 0.f);
    feats[(size_t)g * (KIT * HID) + it * HID + c] = acc;
}

// ---------------- weight prep: Wt[mat][n][k] = bf16(W[mat][k][n]) ---------------
__global__ __launch_bounds__(256) void k_wprep(const float* __restrict__ W,
                                               unsigned short* __restrict__ Wt) {
    int m = blockIdx.x;
    const float* w = W + (size_t)m * HID * HID;
    unsigned short* wt = Wt + (size_t)m * HID * HID;
    for (int idx = threadIdx.x; idx < HID * HID; idx += 256) {
        int k = idx >> 7, n = idx & 127;
        wt[n * HID + k] = f2b(w[k * HID + n]);
    }
}

// ---------------- head layer 1: z1 = relu(feats @ Wh1 + bh1)  [256,640] ---------
__global__ __launch_bounds__(KIT * HID) void k_head1(const float* __restrict__ feats,
                                                     const float* __restrict__ Wh1,
                                                     const float* __restrict__ bh1,
                                                     float* __restrict__ z1) {
    __shared__ float fr[KIT * HID];
    int r = blockIdx.x;
    int c = threadIdx.x;
    fr[c] = feats[r * (KIT * HID) + c];
    __syncthreads();
    float acc = bh1[c];
    for (int k = 0; k < KIT * HID; ++k) acc = fmaf(fr[k], Wh1[k * (KIT * HID) + c], acc);
    z1[r * (KIT * HID) + c] = fmaxf(acc, 0.f);
}

// ---------------- head layer 2: out = z1 @ Wh2 + bh2  [256,10] ------------------
__global__ __launch_bounds__(64) void k_head2(const float* __restrict__ z1,
                                              const float* __restrict__ Wh2,
                                              const float* __restrict__ bh2,
                                              float* __restrict__ out, int total) {
    int gid = blockIdx.x * 64 + threadIdx.x;
    if (gid >= total) return;
    int r = gid / 10, c = gid % 10;
    float acc = bh2[c];
    for (int k = 0; k < KIT * HID; ++k) acc = fmaf(z1[r * (KIT * HID) + k], Wh2[k * 10 + c], acc);
    out[gid] = acc;
}

extern "C" void kernel_launch(void* const* d_in, const int* in_sizes, int n_in,
                              void* d_out, int out_size, void* d_ws, size_t ws_size,
                              hipStream_t stream) {
    const float* X   = (const float*)d_in[0];
    const float* W1  = (const float*)d_in[1];
    const float* b1  = (const float*)d_in[2];
    const float* g1  = (const float*)d_in[3];
    const float* be1 = (const float*)d_in[4];
    const float* W2  = (const float*)d_in[5];
    const float* b2  = (const float*)d_in[6];
    const float* g2  = (const float*)d_in[7];
    const float* be2 = (const float*)d_in[8];
    const float* Wh1 = (const float*)d_in[9];
    const float* bh1 = (const float*)d_in[10];
    const float* Wh2 = (const float*)d_in[11];
    const float* bh2 = (const float*)d_in[12];
    const int* esrc  = (const int*)d_in[13];
    const int* edst  = (const int*)d_in[14];
    const int* batch = (const int*)d_in[15];
    float* out = (float*)d_out;

    const int N = in_sizes[0] / HID;
    const int E = in_sizes[13];

    char* w = (char*)d_ws;
    size_t off = 0;
    auto alloc = [&](size_t bytes) {
        void* p = w + off;
        off += (bytes + 255) & ~(size_t)255;
        return p;
    };
    unsigned short* aggb = (unsigned short*)alloc((size_t)N * HID * 2);
    unsigned short* p1b  = (unsigned short*)alloc((size_t)N * HID * 2);
    unsigned short* p2b  = (unsigned short*)alloc((size_t)N * HID * 2);
    unsigned short* Wt1  = (unsigned short*)alloc((size_t)KIT * HID * HID * 2);
    unsigned short* Wt2  = (unsigned short*)alloc((size_t)KIT * HID * HID * 2);
    float* feats  = (float*)alloc((size_t)NGRAPH * KIT * HID * 4);
    float* z1     = (float*)alloc((size_t)NGRAPH * KIT * HID * 4);
    float* stats  = (float*)alloc((size_t)2 * KIT * 2 * HID * 4);
    float* ssbuf  = (float*)alloc((size_t)2 * KIT * 2 * HID * 4);
    int*   cnt    = (int*)alloc((size_t)N * 4);
    int*   bucket = (int*)alloc((size_t)N * BCAP * 4);

    hipMemsetAsync(cnt, 0, (size_t)N * 4, stream);
    hipMemsetAsync(stats, 0, (size_t)2 * KIT * 2 * HID * 4, stream);

    k_bucket<<<(E + 255) / 256, 256, 0, stream>>>(esrc, edst, cnt, bucket, E);
    k_wprep<<<KIT, 256, 0, stream>>>(W1, Wt1);
    k_wprep<<<KIT, 256, 0, stream>>>(W2, Wt2);

    const int gatherGrid = (N + 3) / 4;
    const int gemmGrid = (N + 63) / 64;
    for (int i = 0; i < KIT; ++i) {
        float* st1 = stats + (size_t)(2 * i) * 256;
        float* st2 = stats + (size_t)(2 * i + 1) * 256;
        float* ss1 = ssbuf + (size_t)(2 * i) * 256;
        float* ss2 = ssbuf + (size_t)(2 * i + 1) * 256;

        if (i == 0) {
            k_gather2<true><<<gatherGrid, 256, 0, stream>>>(X, nullptr, cnt, bucket, aggb, N);
        } else {
            const float* ssp = ssbuf + (size_t)(2 * (i - 1) + 1) * 256;
            k_gather2<false><<<gatherGrid, 256, 0, stream>>>(p2b, ssp, cnt, bucket, aggb, N);
        }
        k_gemm_mfma<false><<<gemmGrid, 256, 0, stream>>>(
            aggb, Wt1 + (size_t)i * HID * HID, b1 + i * HID, nullptr, p1b, st1, N);
        k_fin<<<1, HID, 0, stream>>>(st1, g1 + i * HID, be1 + i * HID, ss1, N);
        k_gemm_mfma<true><<<gemmGrid, 256, 0, stream>>>(
            p1b, Wt2 + (size_t)i * HID * HID, b2 + i * HID, ss1, p2b, st2, N);
        k_fin<<<1, HID, 0, stream>>>(st2, g2 + i * HID, be2 + i * HID, ss2, N);
        k_pool2<<<NGRAPH, HID, 0, stream>>>(p2b, ss2, batch, N, feats, i);
    }
    k_head1<<<NGRAPH, KIT * HID, 0, stream>>>(feats, Wh1, bh1, z1);
    k_head2<<<(NGRAPH * 10 + 63) / 64, 64, 0, stream>>>(z1, Wh2, bh2, out, NGRAPH * 10);
}

// Round 3
// 1727.114 us; speedup vs baseline: 1.3804x; 1.1446x over previous
//
#include <hip/hip_runtime.h>
#include <cstddef>

#define HID 128
#define NGRAPH 256
#define KIT 5
#define BCAP 64
#define BN_EPS 1e-5f

typedef __attribute__((ext_vector_type(8))) short  short8v;
typedef __attribute__((ext_vector_type(8))) unsigned short ushort8v;
typedef __attribute__((ext_vector_type(4))) float  float4v;

__device__ __forceinline__ unsigned short f2b(float f) {
    unsigned int u = __float_as_uint(f);
    u = (u + 0x7FFFu + ((u >> 16) & 1u)) >> 16;
    return (unsigned short)u;
}
__device__ __forceinline__ float b2f(unsigned short b) {
    return __uint_as_float(((unsigned int)b) << 16);
}

// BN finalize, done redundantly per block: ssS[c]=scale, ssS[128+c]=shift
__device__ __forceinline__ void compute_ss(const float* __restrict__ st,
                                           const float* __restrict__ g,
                                           const float* __restrict__ be,
                                           float* ssS, int M, int t) {
    if (t < HID) {
        float invM = 1.f / (float)M;
        float m = st[t] * invM;
        float v = fmaxf(st[HID + t] * invM - m * m, 0.f);
        float sc = rsqrtf(v + BN_EPS) * g[t];
        ssS[t] = sc;
        ssS[HID + t] = fmaf(-m, sc, be[t]);
    }
}

// ---------------- bucket build (CSR-lite, capacity BCAP per node) ----------------
__global__ __launch_bounds__(256) void k_bucket(const int* __restrict__ esrc,
                                                const int* __restrict__ edst,
                                                int* __restrict__ cnt,
                                                int* __restrict__ bucket, int E) {
    int e = blockIdx.x * 256 + threadIdx.x;
    if (e >= E) return;
    int d = edst[e];
    int slot = atomicAdd(cnt + d, 1);
    if (slot < BCAP) bucket[(size_t)d * BCAP + slot] = esrc[e];
}

// ---- fused layer1: [BN_prev+ReLU -> neighbor-sum gather -> GEMM1 -> stats1] ----
// FIRST: hin = fp32 X, no transform. else: hin = bf16 p2, f=relu(v*sc+sh) per term.
// Out = bf16 p1 = agg @ W1 + b1; stats1 += column sum/sumsq (fp32, incl bias).
template<bool FIRST>
__global__ __launch_bounds__(256) void k_layer1(const void* __restrict__ hin,
                                                const float* __restrict__ stp,
                                                const float* __restrict__ gp,
                                                const float* __restrict__ bep,
                                                const int* __restrict__ cnt,
                                                const int* __restrict__ bucket,
                                                const unsigned short* __restrict__ Wt,
                                                const float* __restrict__ bias,
                                                unsigned short* __restrict__ Out,
                                                float* __restrict__ stats, int N) {
    __shared__ float ssS[2 * HID];
    __shared__ float csum[HID], csq[HID];
    const int t = threadIdx.x;
    if (t < HID) { csum[t] = 0.f; csq[t] = 0.f; }
    if constexpr (!FIRST) compute_ss(stp, gp, bep, ssS, N, t);
    __syncthreads();

    const int wave = t >> 6, lane = t & 63;
    const int lr = lane & 15, lk = lane >> 4;
    const int r0 = blockIdx.x * 64 + wave * 16;
    const int arow = r0 + lr;
    const bool rowok = arow < N;
    int deg = 0;
    if (rowok) { deg = cnt[arow]; if (deg > BCAP) deg = BCAP; }
    const int* bp = bucket + (size_t)arow * BCAP;

    // gather: process one 32-col k-block at a time (keeps live regs small)
    short8v af[4];
#pragma unroll
    for (int kb = 0; kb < 4; ++kb) {
        const int k0 = kb * 32 + lk * 8;
        float a[8];
        float4v sc0, sc1, sh0, sh1;
        if constexpr (!FIRST) {
            sc0 = *(const float4v*)&ssS[k0];       sc1 = *(const float4v*)&ssS[k0 + 4];
            sh0 = *(const float4v*)&ssS[HID + k0]; sh1 = *(const float4v*)&ssS[HID + k0 + 4];
        }
        if (rowok) {
            if constexpr (FIRST) {
                const float* xp = (const float*)hin + (size_t)arow * HID + k0;
                const float4v v0 = *(const float4v*)xp;
                const float4v v1 = *(const float4v*)(xp + 4);
#pragma unroll
                for (int j = 0; j < 4; ++j) { a[j] = v0[j]; a[4 + j] = v1[j]; }
            } else {
                const ushort8v raw = *(const ushort8v*)((const unsigned short*)hin + (size_t)arow * HID + k0);
#pragma unroll
                for (int j = 0; j < 4; ++j) {
                    a[j]     = fmaxf(fmaf(b2f(raw[j]),     sc0[j], sh0[j]), 0.f);
                    a[4 + j] = fmaxf(fmaf(b2f(raw[j + 4]), sc1[j], sh1[j]), 0.f);
                }
            }
        } else {
#pragma unroll
            for (int j = 0; j < 8; ++j) a[j] = 0.f;
        }
        for (int j = 0; j < deg; ++j) {
            const int src = bp[j];
            if constexpr (FIRST) {
                const float* xp = (const float*)hin + (size_t)src * HID + k0;
                const float4v v0 = *(const float4v*)xp;
                const float4v v1 = *(const float4v*)(xp + 4);
#pragma unroll
                for (int q = 0; q < 4; ++q) { a[q] += v0[q]; a[4 + q] += v1[q]; }
            } else {
                const ushort8v raw = *(const ushort8v*)((const unsigned short*)hin + (size_t)src * HID + k0);
#pragma unroll
                for (int q = 0; q < 4; ++q) {
                    a[q]     += fmaxf(fmaf(b2f(raw[q]),     sc0[q], sh0[q]), 0.f);
                    a[4 + q] += fmaxf(fmaf(b2f(raw[q + 4]), sc1[q], sh1[q]), 0.f);
                }
            }
        }
        ushort8v pk;
#pragma unroll
        for (int j = 0; j < 8; ++j) pk[j] = f2b(a[j]);
        af[kb] = *reinterpret_cast<short8v*>(&pk);
    }

    // GEMM: 8 column tiles of 16
    float4v acc[8];
#pragma unroll
    for (int ct = 0; ct < 8; ++ct) {
        float4v c = {0.f, 0.f, 0.f, 0.f};
        const unsigned short* bw = Wt + (size_t)(ct * 16 + lr) * HID + lk * 8;
#pragma unroll
        for (int kb = 0; kb < 4; ++kb) {
            short8v bf = *reinterpret_cast<const short8v*>(bw + kb * 32);
            c = __builtin_amdgcn_mfma_f32_16x16x32_bf16(af[kb], bf, c, 0, 0, 0);
        }
        acc[ct] = c;
    }

#pragma unroll
    for (int ct = 0; ct < 8; ++ct) {
        const int col = ct * 16 + lr;
        const float b = bias[col];
        float s = 0.f, q = 0.f;
#pragma unroll
        for (int j = 0; j < 4; ++j) {
            const int row = r0 + lk * 4 + j;
            if (row < N) {
                const float o = acc[ct][j] + b;
                Out[(size_t)row * HID + col] = f2b(o);
                s += o; q += o * o;
            }
        }
        s += __shfl_xor(s, 16); s += __shfl_xor(s, 32);
        q += __shfl_xor(q, 16); q += __shfl_xor(q, 32);
        if (lk == 0) { atomicAdd(&csum[col], s); atomicAdd(&csq[col], q); }
    }
    __syncthreads();
    if (t < HID) {
        atomicAdd(stats + t, csum[t]);
        atomicAdd(stats + HID + t, csq[t]);
    }
}

// ---- layer2: [fin1 inline -> BN1+ReLU on p1 -> GEMM2 -> p2 bf16, stats2] -------
__global__ __launch_bounds__(256) void k_layer2(const unsigned short* __restrict__ A,
                                                const float* __restrict__ st_in,
                                                const float* __restrict__ g_in,
                                                const float* __restrict__ be_in,
                                                const unsigned short* __restrict__ Wt,
                                                const float* __restrict__ bias,
                                                unsigned short* __restrict__ Out,
                                                float* __restrict__ stats, int M) {
    __shared__ float ssS[2 * HID];
    __shared__ float csum[HID], csq[HID];
    const int t = threadIdx.x;
    if (t < HID) { csum[t] = 0.f; csq[t] = 0.f; }
    compute_ss(st_in, g_in, be_in, ssS, M, t);
    __syncthreads();

    const int wave = t >> 6, lane = t & 63;
    const int lr = lane & 15, lk = lane >> 4;
    const int r0 = blockIdx.x * 64 + wave * 16;
    const int arow = r0 + lr;
    const bool rowok = arow < M;

    short8v af[4];
    const unsigned short* ap = A + (size_t)arow * HID + lk * 8;
#pragma unroll
    for (int kb = 0; kb < 4; ++kb) {
        ushort8v raw;
        if (rowok) raw = *reinterpret_cast<const ushort8v*>(ap + kb * 32);
        else       raw = (ushort8v)(unsigned short)0;
        const int k0 = kb * 32 + lk * 8;
        const float4v sc0 = *(const float4v*)&ssS[k0];
        const float4v sc1 = *(const float4v*)&ssS[k0 + 4];
        const float4v sh0 = *(const float4v*)&ssS[HID + k0];
        const float4v sh1 = *(const float4v*)&ssS[HID + k0 + 4];
        ushort8v pk;
#pragma unroll
        for (int j = 0; j < 4; ++j) {
            pk[j]     = f2b(fmaxf(fmaf(b2f(raw[j]),     sc0[j], sh0[j]), 0.f));
            pk[j + 4] = f2b(fmaxf(fmaf(b2f(raw[j + 4]), sc1[j], sh1[j]), 0.f));
        }
        af[kb] = *reinterpret_cast<short8v*>(&pk);
    }

    float4v acc[8];
#pragma unroll
    for (int ct = 0; ct < 8; ++ct) {
        float4v c = {0.f, 0.f, 0.f, 0.f};
        const unsigned short* bw = Wt + (size_t)(ct * 16 + lr) * HID + lk * 8;
#pragma unroll
        for (int kb = 0; kb < 4; ++kb) {
            short8v bf = *reinterpret_cast<const short8v*>(bw + kb * 32);
            c = __builtin_amdgcn_mfma_f32_16x16x32_bf16(af[kb], bf, c, 0, 0, 0);
        }
        acc[ct] = c;
    }

#pragma unroll
    for (int ct = 0; ct < 8; ++ct) {
        const int col = ct * 16 + lr;
        const float b = bias[col];
        float s = 0.f, q = 0.f;
#pragma unroll
        for (int j = 0; j < 4; ++j) {
            const int row = r0 + lk * 4 + j;
            if (row < M) {
                const float o = acc[ct][j] + b;
                Out[(size_t)row * HID + col] = f2b(o);
                s += o; q += o * o;
            }
        }
        s += __shfl_xor(s, 16); s += __shfl_xor(s, 32);
        q += __shfl_xor(q, 16); q += __shfl_xor(q, 32);
        if (lk == 0) { atomicAdd(&csum[col], s); atomicAdd(&csq[col], q); }
    }
    __syncthreads();
    if (t < HID) {
        atomicAdd(stats + t, csum[t]);
        atomicAdd(stats + HID + t, csq[t]);
    }
}

// ---- pool: [fin2 inline -> BN2+ReLU -> per-graph add-pool], grid (256, 8) ------
__global__ __launch_bounds__(HID) void k_pool(const unsigned short* __restrict__ p2,
                                              const float* __restrict__ st,
                                              const float* __restrict__ g,
                                              const float* __restrict__ be,
                                              const int* __restrict__ batch,
                                              int N, float* __restrict__ feats, int it) {
    __shared__ float ssS[2 * HID];
    const int t = threadIdx.x;
    compute_ss(st, g, be, ssS, N, t);
    __syncthreads();
    const int gph = blockIdx.x;
    int a = 0, b = N;
    while (a < b) { int m = (a + b) >> 1; if (batch[m] < gph) a = m + 1; else b = m; }
    const int lo = a;
    b = N;
    while (a < b) { int m = (a + b) >> 1; if (batch[m] < gph + 1) a = m + 1; else b = m; }
    const int hi = a;
    const int len = hi - lo;
    const int r0 = lo + (int)(((long long)len * blockIdx.y) >> 3);
    const int r1 = lo + (int)(((long long)len * (blockIdx.y + 1)) >> 3);
    const float sc = ssS[t], sh = ssS[HID + t];
    float acc = 0.f;
    for (int r = r0; r < r1; ++r)
        acc += fmaxf(fmaf(b2f(p2[(size_t)r * HID + t]), sc, sh), 0.f);
    if (r1 > r0)
        atomicAdd(&feats[(size_t)gph * (KIT * HID) + it * HID + t], acc);
}

// ---------------- weight prep: Wt[mat][n][k] = bf16(W[mat][k][n]) ---------------
__global__ __launch_bounds__(256) void k_wprep(const float* __restrict__ W,
                                               unsigned short* __restrict__ Wt) {
    int m = blockIdx.x;
    const float* w = W + (size_t)m * HID * HID;
    unsigned short* wt = Wt + (size_t)m * HID * HID;
    for (int idx = threadIdx.x; idx < HID * HID; idx += 256) {
        int k = idx >> 7, n = idx & 127;
        wt[n * HID + k] = f2b(w[k * HID + n]);
    }
}

// ---------------- head layer 1: z1 = relu(feats @ Wh1 + bh1)  [256,640] ---------
__global__ __launch_bounds__(KIT * HID) void k_head1(const float* __restrict__ feats,
                                                     const float* __restrict__ Wh1,
                                                     const float* __restrict__ bh1,
                                                     float* __restrict__ z1) {
    __shared__ float fr[KIT * HID];
    int r = blockIdx.x;
    int c = threadIdx.x;
    fr[c] = feats[r * (KIT * HID) + c];
    __syncthreads();
    float acc = bh1[c];
    for (int k = 0; k < KIT * HID; ++k) acc = fmaf(fr[k], Wh1[k * (KIT * HID) + c], acc);
    z1[r * (KIT * HID) + c] = fmaxf(acc, 0.f);
}

// ---------------- head layer 2: out = z1 @ Wh2 + bh2  [256,10] ------------------
__global__ __launch_bounds__(64) void k_head2(const float* __restrict__ z1,
                                              const float* __restrict__ Wh2,
                                              const float* __restrict__ bh2,
                                              float* __restrict__ out, int total) {
    int gid = blockIdx.x * 64 + threadIdx.x;
    if (gid >= total) return;
    int r = gid / 10, c = gid % 10;
    float acc = bh2[c];
    for (int k = 0; k < KIT * HID; ++k) acc = fmaf(z1[r * (KIT * HID) + k], Wh2[k * 10 + c], acc);
    out[gid] = acc;
}

extern "C" void kernel_launch(void* const* d_in, const int* in_sizes, int n_in,
                              void* d_out, int out_size, void* d_ws, size_t ws_size,
                              hipStream_t stream) {
    const float* X   = (const float*)d_in[0];
    const float* W1  = (const float*)d_in[1];
    const float* b1  = (const float*)d_in[2];
    const float* g1  = (const float*)d_in[3];
    const float* be1 = (const float*)d_in[4];
    const float* W2  = (const float*)d_in[5];
    const float* b2  = (const float*)d_in[6];
    const float* g2  = (const float*)d_in[7];
    const float* be2 = (const float*)d_in[8];
    const float* Wh1 = (const float*)d_in[9];
    const float* bh1 = (const float*)d_in[10];
    const float* Wh2 = (const float*)d_in[11];
    const float* bh2 = (const float*)d_in[12];
    const int* esrc  = (const int*)d_in[13];
    const int* edst  = (const int*)d_in[14];
    const int* batch = (const int*)d_in[15];
    float* out = (float*)d_out;

    const int N = in_sizes[0] / HID;
    const int E = in_sizes[13];

    char* w = (char*)d_ws;
    size_t off = 0;
    auto alloc = [&](size_t bytes) {
        void* p = w + off;
        off += (bytes + 255) & ~(size_t)255;
        return p;
    };
    unsigned short* p1b  = (unsigned short*)alloc((size_t)N * HID * 2);
    unsigned short* p2b  = (unsigned short*)alloc((size_t)N * HID * 2);
    unsigned short* Wt1  = (unsigned short*)alloc((size_t)KIT * HID * HID * 2);
    unsigned short* Wt2  = (unsigned short*)alloc((size_t)KIT * HID * HID * 2);
    float* feats  = (float*)alloc((size_t)NGRAPH * KIT * HID * 4);
    float* z1     = (float*)alloc((size_t)NGRAPH * KIT * HID * 4);
    float* stats  = (float*)alloc((size_t)2 * KIT * 2 * HID * 4);
    int*   cnt    = (int*)alloc((size_t)N * 4);
    int*   bucket = (int*)alloc((size_t)N * BCAP * 4);

    hipMemsetAsync(cnt, 0, (size_t)N * 4, stream);
    hipMemsetAsync(stats, 0, (size_t)2 * KIT * 2 * HID * 4, stream);
    hipMemsetAsync(feats, 0, (size_t)NGRAPH * KIT * HID * 4, stream);

    k_bucket<<<(E + 255) / 256, 256, 0, stream>>>(esrc, edst, cnt, bucket, E);
    k_wprep<<<KIT, 256, 0, stream>>>(W1, Wt1);
    k_wprep<<<KIT, 256, 0, stream>>>(W2, Wt2);

    const int gemmGrid = (N + 63) / 64;
    for (int i = 0; i < KIT; ++i) {
        float* st1 = stats + (size_t)(2 * i) * 256;
        float* st2 = stats + (size_t)(2 * i + 1) * 256;

        if (i == 0) {
            k_layer1<true><<<gemmGrid, 256, 0, stream>>>(
                X, nullptr, nullptr, nullptr, cnt, bucket,
                Wt1, b1, p1b, st1, N);
        } else {
            const float* stp = stats + (size_t)(2 * (i - 1) + 1) * 256;
            k_layer1<false><<<gemmGrid, 256, 0, stream>>>(
                p2b, stp, g2 + (i - 1) * HID, be2 + (i - 1) * HID, cnt, bucket,
                Wt1 + (size_t)i * HID * HID, b1 + i * HID, p1b, st1, N);
        }
        k_layer2<<<gemmGrid, 256, 0, stream>>>(
            p1b, st1, g1 + i * HID, be1 + i * HID,
            Wt2 + (size_t)i * HID * HID, b2 + i * HID, p2b, st2, N);
        k_pool<<<dim3(NGRAPH, 8), HID, 0, stream>>>(
            p2b, st2, g2 + i * HID, be2 + i * HID, batch, N, feats, i);
    }
    k_head1<<<NGRAPH, KIT * HID, 0, stream>>>(feats, Wh1, bh1, z1);
    k_head2<<<(NGRAPH * 10 + 63) / 64, 64, 0, stream>>>(z1, Wh2, bh2, out, NGRAPH * 10);
}

// Round 4
// 1437.803 us; speedup vs baseline: 1.6582x; 1.2012x over previous
//
#include <hip/hip_runtime.h>
#include <cstddef>

#define HID 128
#define NGRAPH 256
#define KIT 5
#define BCAP 64
#define BN_EPS 1e-5f

typedef __attribute__((ext_vector_type(8))) short  short8v;
typedef __attribute__((ext_vector_type(8))) unsigned short ushort8v;
typedef __attribute__((ext_vector_type(4))) unsigned short ushort4v;
typedef __attribute__((ext_vector_type(4))) float  float4v;

__device__ __forceinline__ unsigned short f2b(float f) {
    unsigned int u = __float_as_uint(f);
    u = (u + 0x7FFFu + ((u >> 16) & 1u)) >> 16;
    return (unsigned short)u;
}
__device__ __forceinline__ float b2f(unsigned short b) {
    return __uint_as_float(((unsigned int)b) << 16);
}

// BN finalize, done redundantly per block: ssS[c]=scale, ssS[128+c]=shift
__device__ __forceinline__ void compute_ss(const float* __restrict__ st,
                                           const float* __restrict__ g,
                                           const float* __restrict__ be,
                                           float* ssS, int M, int t) {
    if (t < HID) {
        float invM = 1.f / (float)M;
        float m = st[t] * invM;
        float v = fmaxf(st[HID + t] * invM - m * m, 0.f);
        float sc = rsqrtf(v + BN_EPS) * g[t];
        ssS[t] = sc;
        ssS[HID + t] = fmaf(-m, sc, be[t]);
    }
}

// ---------------- bucket build (CSR-lite, capacity BCAP per node) ----------------
__global__ __launch_bounds__(256) void k_bucket(const int* __restrict__ esrc,
                                                const int* __restrict__ edst,
                                                int* __restrict__ cnt,
                                                int* __restrict__ bucket, int E) {
    int e = blockIdx.x * 256 + threadIdx.x;
    if (e >= E) return;
    int d = edst[e];
    int slot = atomicAdd(cnt + d, 1);
    if (slot < BCAP) bucket[(size_t)d * BCAP + slot] = esrc[e];
}

// ---- fused layer1: [BN_prev+ReLU -> neighbor-sum gather -> GEMM1 -> stats1] ----
// Gather: wave-per-row (16 rows per wave, sequential), 4 edges (2 for fp32 FIRST)
// per iteration as full-row coalesced loads; uniform deg per wave (no divergence).
// Rows land in XOR-swizzled LDS; phase 2 reads MFMA fragments (no block barrier
// needed between phases: each wave owns its 16 LDS rows).
template<bool FIRST>
__global__ __launch_bounds__(256) void k_layer1(const void* __restrict__ hin,
                                                const float* __restrict__ stp,
                                                const float* __restrict__ gp,
                                                const float* __restrict__ bep,
                                                const int* __restrict__ cnt,
                                                const int* __restrict__ bucket,
                                                const unsigned short* __restrict__ Wt,
                                                const float* __restrict__ bias,
                                                unsigned short* __restrict__ Out,
                                                float* __restrict__ stats, int N) {
    __shared__ float ssS[2 * HID];
    __shared__ float csum[HID], csq[HID];
    __shared__ unsigned short As[64 * HID];   // bf16 agg rows, XOR-swizzled
    const int t = threadIdx.x;
    if (t < HID) { csum[t] = 0.f; csq[t] = 0.f; }
    if constexpr (!FIRST) compute_ss(stp, gp, bep, ssS, N, t);
    __syncthreads();

    const int wave = t >> 6, lane = t & 63;
    char* Abase = (char*)As + wave * 16 * 256;   // this wave's 16 rows

    // ------------------ phase 1: gather ------------------
    if constexpr (!FIRST) {
        const int cg  = lane & 15;   // col group: cols cg*8 .. cg*8+7
        const int grp = lane >> 4;   // edge-slot group 0..3
        float sc[8], sh[8];
#pragma unroll
        for (int q = 0; q < 8; ++q) { sc[q] = ssS[cg * 8 + q]; sh[q] = ssS[HID + cg * 8 + q]; }
        const unsigned short* H = (const unsigned short*)hin;
        for (int rr = 0; rr < 16; ++rr) {
            const int row = blockIdx.x * 64 + wave * 16 + rr;
            const bool rowok = row < N;
            int deg = 0;
            if (rowok) { deg = cnt[row]; if (deg > BCAP) deg = BCAP; }
            const int* bp = bucket + (size_t)row * BCAP;
            int sb = (lane < deg) ? bp[lane] : 0;
            float a[8];
#pragma unroll
            for (int q = 0; q < 8; ++q) a[q] = 0.f;
            if (rowok && grp == 0) {   // self term (eps=0 -> weight 1)
                const ushort8v raw = *(const ushort8v*)(H + (size_t)row * HID + cg * 8);
#pragma unroll
                for (int q = 0; q < 8; ++q)
                    a[q] = fmaxf(fmaf(b2f(raw[q]), sc[q], sh[q]), 0.f);
            }
            const int nIt = (deg + 3) >> 2;
            for (int it = 0; it < nIt; ++it) {
                const int slot = it * 4 + grp;
                const int src = __shfl(sb, slot);          // 0 for slot>=deg
                const float m = (slot < deg) ? 1.f : 0.f;
                const ushort8v raw = *(const ushort8v*)(H + (size_t)src * HID + cg * 8);
#pragma unroll
                for (int q = 0; q < 8; ++q)
                    a[q] = fmaf(fmaxf(fmaf(b2f(raw[q]), sc[q], sh[q]), 0.f), m, a[q]);
            }
#pragma unroll
            for (int q = 0; q < 8; ++q) {
                a[q] += __shfl_xor(a[q], 16);
                a[q] += __shfl_xor(a[q], 32);
            }
            if (grp == 0) {
                ushort8v pk;
#pragma unroll
                for (int q = 0; q < 8; ++q) pk[q] = f2b(a[q]);
                const int byt = (rr * 256 + cg * 16) ^ ((rr & 7) << 4);
                *(ushort8v*)(Abase + byt) = pk;
            }
        }
    } else {
        const int cg  = lane & 31;   // col group: cols cg*4 .. cg*4+3 (fp32 rows)
        const int grp = lane >> 5;   // edge-slot group 0..1
        const float* H = (const float*)hin;
        for (int rr = 0; rr < 16; ++rr) {
            const int row = blockIdx.x * 64 + wave * 16 + rr;
            const bool rowok = row < N;
            int deg = 0;
            if (rowok) { deg = cnt[row]; if (deg > BCAP) deg = BCAP; }
            const int* bp = bucket + (size_t)row * BCAP;
            int sb = (lane < deg) ? bp[lane] : 0;
            float a[4] = {0.f, 0.f, 0.f, 0.f};
            if (rowok && grp == 0) {
                const float4v v = *(const float4v*)(H + (size_t)row * HID + cg * 4);
#pragma unroll
                for (int q = 0; q < 4; ++q) a[q] = v[q];
            }
            const int nIt = (deg + 1) >> 1;
            for (int it = 0; it < nIt; ++it) {
                const int slot = it * 2 + grp;
                const int src = __shfl(sb, slot);
                const float m = (slot < deg) ? 1.f : 0.f;
                const float4v v = *(const float4v*)(H + (size_t)src * HID + cg * 4);
#pragma unroll
                for (int q = 0; q < 4; ++q) a[q] = fmaf(v[q], m, a[q]);
            }
#pragma unroll
            for (int q = 0; q < 4; ++q) a[q] += __shfl_xor(a[q], 32);
            if (grp == 0) {
                ushort4v pk;
#pragma unroll
                for (int q = 0; q < 4; ++q) pk[q] = f2b(a[q]);
                const int byt = (rr * 256 + cg * 8) ^ ((rr & 7) << 4);
                *(ushort4v*)(Abase + byt) = pk;
            }
        }
    }

    // ------------------ phase 2: GEMM from LDS ------------------
    const int lr = lane & 15, lk = lane >> 4;
    const int r0 = blockIdx.x * 64 + wave * 16;
    short8v af[4];
#pragma unroll
    for (int kb = 0; kb < 4; ++kb) {
        const int byt = (lr * 256 + kb * 64 + lk * 16) ^ ((lr & 7) << 4);
        af[kb] = *(const short8v*)(Abase + byt);
    }
    float4v acc[8];
#pragma unroll
    for (int ct = 0; ct < 8; ++ct) {
        float4v c = {0.f, 0.f, 0.f, 0.f};
        const unsigned short* bw = Wt + (size_t)(ct * 16 + lr) * HID + lk * 8;
#pragma unroll
        for (int kb = 0; kb < 4; ++kb) {
            short8v bf = *reinterpret_cast<const short8v*>(bw + kb * 32);
            c = __builtin_amdgcn_mfma_f32_16x16x32_bf16(af[kb], bf, c, 0, 0, 0);
        }
        acc[ct] = c;
    }

#pragma unroll
    for (int ct = 0; ct < 8; ++ct) {
        const int col = ct * 16 + lr;
        const float b = bias[col];
        float s = 0.f, q = 0.f;
#pragma unroll
        for (int j = 0; j < 4; ++j) {
            const int row = r0 + lk * 4 + j;
            if (row < N) {
                const float o = acc[ct][j] + b;
                Out[(size_t)row * HID + col] = f2b(o);
                s += o; q += o * o;
            }
        }
        s += __shfl_xor(s, 16); s += __shfl_xor(s, 32);
        q += __shfl_xor(q, 16); q += __shfl_xor(q, 32);
        if (lk == 0) { atomicAdd(&csum[col], s); atomicAdd(&csq[col], q); }
    }
    __syncthreads();
    if (t < HID) {
        atomicAdd(stats + t, csum[t]);
        atomicAdd(stats + HID + t, csq[t]);
    }
}

// ---- layer2: [fin1 inline -> BN1+ReLU on p1 -> GEMM2 -> p2 bf16, stats2] -------
__global__ __launch_bounds__(256) void k_layer2(const unsigned short* __restrict__ A,
                                                const float* __restrict__ st_in,
                                                const float* __restrict__ g_in,
                                                const float* __restrict__ be_in,
                                                const unsigned short* __restrict__ Wt,
                                                const float* __restrict__ bias,
                                                unsigned short* __restrict__ Out,
                                                float* __restrict__ stats, int M) {
    __shared__ float ssS[2 * HID];
    __shared__ float csum[HID], csq[HID];
    const int t = threadIdx.x;
    if (t < HID) { csum[t] = 0.f; csq[t] = 0.f; }
    compute_ss(st_in, g_in, be_in, ssS, M, t);
    __syncthreads();

    const int wave = t >> 6, lane = t & 63;
    const int lr = lane & 15, lk = lane >> 4;
    const int r0 = blockIdx.x * 64 + wave * 16;
    const int arow = r0 + lr;
    const bool rowok = arow < M;

    short8v af[4];
    const unsigned short* ap = A + (size_t)arow * HID + lk * 8;
#pragma unroll
    for (int kb = 0; kb < 4; ++kb) {
        ushort8v raw;
        if (rowok) raw = *reinterpret_cast<const ushort8v*>(ap + kb * 32);
        else       raw = (ushort8v)(unsigned short)0;
        const int k0 = kb * 32 + lk * 8;
        const float4v sc0 = *(const float4v*)&ssS[k0];
        const float4v sc1 = *(const float4v*)&ssS[k0 + 4];
        const float4v sh0 = *(const float4v*)&ssS[HID + k0];
        const float4v sh1 = *(const float4v*)&ssS[HID + k0 + 4];
        ushort8v pk;
#pragma unroll
        for (int j = 0; j < 4; ++j) {
            pk[j]     = f2b(fmaxf(fmaf(b2f(raw[j]),     sc0[j], sh0[j]), 0.f));
            pk[j + 4] = f2b(fmaxf(fmaf(b2f(raw[j + 4]), sc1[j], sh1[j]), 0.f));
        }
        af[kb] = *reinterpret_cast<short8v*>(&pk);
    }

    float4v acc[8];
#pragma unroll
    for (int ct = 0; ct < 8; ++ct) {
        float4v c = {0.f, 0.f, 0.f, 0.f};
        const unsigned short* bw = Wt + (size_t)(ct * 16 + lr) * HID + lk * 8;
#pragma unroll
        for (int kb = 0; kb < 4; ++kb) {
            short8v bf = *reinterpret_cast<const short8v*>(bw + kb * 32);
            c = __builtin_amdgcn_mfma_f32_16x16x32_bf16(af[kb], bf, c, 0, 0, 0);
        }
        acc[ct] = c;
    }

#pragma unroll
    for (int ct = 0; ct < 8; ++ct) {
        const int col = ct * 16 + lr;
        const float b = bias[col];
        float s = 0.f, q = 0.f;
#pragma unroll
        for (int j = 0; j < 4; ++j) {
            const int row = r0 + lk * 4 + j;
            if (row < M) {
                const float o = acc[ct][j] + b;
                Out[(size_t)row * HID + col] = f2b(o);
                s += o; q += o * o;
            }
        }
        s += __shfl_xor(s, 16); s += __shfl_xor(s, 32);
        q += __shfl_xor(q, 16); q += __shfl_xor(q, 32);
        if (lk == 0) { atomicAdd(&csum[col], s); atomicAdd(&csq[col], q); }
    }
    __syncthreads();
    if (t < HID) {
        atomicAdd(stats + t, csum[t]);
        atomicAdd(stats + HID + t, csq[t]);
    }
}

// ---- pool: [fin2 inline -> BN2+ReLU -> per-graph add-pool], grid (256, 8) ------
__global__ __launch_bounds__(HID) void k_pool(const unsigned short* __restrict__ p2,
                                              const float* __restrict__ st,
                                              const float* __restrict__ g,
                                              const float* __restrict__ be,
                                              const int* __restrict__ batch,
                                              int N, float* __restrict__ feats, int it) {
    __shared__ float ssS[2 * HID];
    const int t = threadIdx.x;
    compute_ss(st, g, be, ssS, N, t);
    __syncthreads();
    const int gph = blockIdx.x;
    int a = 0, b = N;
    while (a < b) { int m = (a + b) >> 1; if (batch[m] < gph) a = m + 1; else b = m; }
    const int lo = a;
    b = N;
    while (a < b) { int m = (a + b) >> 1; if (batch[m] < gph + 1) a = m + 1; else b = m; }
    const int hi = a;
    const int len = hi - lo;
    const int r0 = lo + (int)(((long long)len * blockIdx.y) >> 3);
    const int r1 = lo + (int)(((long long)len * (blockIdx.y + 1)) >> 3);
    const float sc = ssS[t], sh = ssS[HID + t];
    float acc = 0.f;
    for (int r = r0; r < r1; ++r)
        acc += fmaxf(fmaf(b2f(p2[(size_t)r * HID + t]), sc, sh), 0.f);
    if (r1 > r0)
        atomicAdd(&feats[(size_t)gph * (KIT * HID) + it * HID + t], acc);
}

// ---------------- weight prep: Wt[mat][n][k] = bf16(W[mat][k][n]) ---------------
__global__ __launch_bounds__(256) void k_wprep(const float* __restrict__ W,
                                               unsigned short* __restrict__ Wt) {
    int m = blockIdx.x;
    const float* w = W + (size_t)m * HID * HID;
    unsigned short* wt = Wt + (size_t)m * HID * HID;
    for (int idx = threadIdx.x; idx < HID * HID; idx += 256) {
        int k = idx >> 7, n = idx & 127;
        wt[n * HID + k] = f2b(w[k * HID + n]);
    }
}

// ---------------- head layer 1: z1 = relu(feats @ Wh1 + bh1)  [256,640] ---------
__global__ __launch_bounds__(KIT * HID) void k_head1(const float* __restrict__ feats,
                                                     const float* __restrict__ Wh1,
                                                     const float* __restrict__ bh1,
                                                     float* __restrict__ z1) {
    __shared__ float fr[KIT * HID];
    int r = blockIdx.x;
    int c = threadIdx.x;
    fr[c] = feats[r * (KIT * HID) + c];
    __syncthreads();
    float acc = bh1[c];
    for (int k = 0; k < KIT * HID; ++k) acc = fmaf(fr[k], Wh1[k * (KIT * HID) + c], acc);
    z1[r * (KIT * HID) + c] = fmaxf(acc, 0.f);
}

// ---------------- head layer 2: out = z1 @ Wh2 + bh2  [256,10] ------------------
__global__ __launch_bounds__(64) void k_head2(const float* __restrict__ z1,
                                              const float* __restrict__ Wh2,
                                              const float* __restrict__ bh2,
                                              float* __restrict__ out, int total) {
    int gid = blockIdx.x * 64 + threadIdx.x;
    if (gid >= total) return;
    int r = gid / 10, c = gid % 10;
    float acc = bh2[c];
    for (int k = 0; k < KIT * HID; ++k) acc = fmaf(z1[r * (KIT * HID) + k], Wh2[k * 10 + c], acc);
    out[gid] = acc;
}

extern "C" void kernel_launch(void* const* d_in, const int* in_sizes, int n_in,
                              void* d_out, int out_size, void* d_ws, size_t ws_size,
                              hipStream_t stream) {
    const float* X   = (const float*)d_in[0];
    const float* W1  = (const float*)d_in[1];
    const float* b1  = (const float*)d_in[2];
    const float* g1  = (const float*)d_in[3];
    const float* be1 = (const float*)d_in[4];
    const float* W2  = (const float*)d_in[5];
    const float* b2  = (const float*)d_in[6];
    const float* g2  = (const float*)d_in[7];
    const float* be2 = (const float*)d_in[8];
    const float* Wh1 = (const float*)d_in[9];
    const float* bh1 = (const float*)d_in[10];
    const float* Wh2 = (const float*)d_in[11];
    const float* bh2 = (const float*)d_in[12];
    const int* esrc  = (const int*)d_in[13];
    const int* edst  = (const int*)d_in[14];
    const int* batch = (const int*)d_in[15];
    float* out = (float*)d_out;

    const int N = in_sizes[0] / HID;
    const int E = in_sizes[13];

    char* w = (char*)d_ws;
    size_t off = 0;
    auto alloc = [&](size_t bytes) {
        void* p = w + off;
        off += (bytes + 255) & ~(size_t)255;
        return p;
    };
    unsigned short* p1b  = (unsigned short*)alloc((size_t)N * HID * 2);
    unsigned short* p2b  = (unsigned short*)alloc((size_t)N * HID * 2);
    unsigned short* Wt1  = (unsigned short*)alloc((size_t)KIT * HID * HID * 2);
    unsigned short* Wt2  = (unsigned short*)alloc((size_t)KIT * HID * HID * 2);
    float* feats  = (float*)alloc((size_t)NGRAPH * KIT * HID * 4);
    float* z1     = (float*)alloc((size_t)NGRAPH * KIT * HID * 4);
    float* stats  = (float*)alloc((size_t)2 * KIT * 2 * HID * 4);
    int*   cnt    = (int*)alloc((size_t)N * 4);
    int*   bucket = (int*)alloc((size_t)N * BCAP * 4);

    hipMemsetAsync(cnt, 0, (size_t)N * 4, stream);
    hipMemsetAsync(stats, 0, (size_t)2 * KIT * 2 * HID * 4, stream);
    hipMemsetAsync(feats, 0, (size_t)NGRAPH * KIT * HID * 4, stream);

    k_bucket<<<(E + 255) / 256, 256, 0, stream>>>(esrc, edst, cnt, bucket, E);
    k_wprep<<<KIT, 256, 0, stream>>>(W1, Wt1);
    k_wprep<<<KIT, 256, 0, stream>>>(W2, Wt2);

    const int gemmGrid = (N + 63) / 64;
    for (int i = 0; i < KIT; ++i) {
        float* st1 = stats + (size_t)(2 * i) * 256;
        float* st2 = stats + (size_t)(2 * i + 1) * 256;

        if (i == 0) {
            k_layer1<true><<<gemmGrid, 256, 0, stream>>>(
                X, nullptr, nullptr, nullptr, cnt, bucket,
                Wt1, b1, p1b, st1, N);
        } else {
            const float* stp = stats + (size_t)(2 * (i - 1) + 1) * 256;
            k_layer1<false><<<gemmGrid, 256, 0, stream>>>(
                p2b, stp, g2 + (i - 1) * HID, be2 + (i - 1) * HID, cnt, bucket,
                Wt1 + (size_t)i * HID * HID, b1 + i * HID, p1b, st1, N);
        }
        k_layer2<<<gemmGrid, 256, 0, stream>>>(
            p1b, st1, g1 + i * HID, be1 + i * HID,
            Wt2 + (size_t)i * HID * HID, b2 + i * HID, p2b, st2, N);
        k_pool<<<dim3(NGRAPH, 8), HID, 0, stream>>>(
            p2b, st2, g2 + i * HID, be2 + i * HID, batch, N, feats, i);
    }
    k_head1<<<NGRAPH, KIT * HID, 0, stream>>>(feats, Wh1, bh1, z1);
    k_head2<<<(NGRAPH * 10 + 63) / 64, 64, 0, stream>>>(z1, Wh2, bh2, out, NGRAPH * 10);
}

// Round 5
// 1292.857 us; speedup vs baseline: 1.8441x; 1.1121x over previous
//
#include <hip/hip_runtime.h>
#include <cstddef>

#define HID 128
#define NGRAPH 256
#define KIT 5
#define BCAP 64
#define BN_EPS 1e-5f

typedef __attribute__((ext_vector_type(8))) short  short8v;
typedef __attribute__((ext_vector_type(8))) unsigned short ushort8v;
typedef __attribute__((ext_vector_type(4))) unsigned short ushort4v;
typedef __attribute__((ext_vector_type(4))) float  float4v;

__device__ __forceinline__ unsigned short f2b(float f) {
    unsigned int u = __float_as_uint(f);
    u = (u + 0x7FFFu + ((u >> 16) & 1u)) >> 16;
    return (unsigned short)u;
}
__device__ __forceinline__ float b2f(unsigned short b) {
    return __uint_as_float(((unsigned int)b) << 16);
}
__device__ __forceinline__ int uminc(int v, int hi) {   // clamp via unsigned min
    return (int)min((unsigned)v, (unsigned)hi);
}

// BN finalize, done redundantly per block: ssS[c]=scale, ssS[128+c]=shift
__device__ __forceinline__ void compute_ss(const float* __restrict__ st,
                                           const float* __restrict__ g,
                                           const float* __restrict__ be,
                                           float* ssS, int M, int t) {
    if (t < HID) {
        float invM = 1.f / (float)M;
        float m = st[t] * invM;
        float v = fmaxf(st[HID + t] * invM - m * m, 0.f);
        float sc = rsqrtf(v + BN_EPS) * g[t];
        ssS[t] = sc;
        ssS[HID + t] = fmaf(-m, sc, be[t]);
    }
}

// ---------------- bucket build (CSR-lite, capacity BCAP per node) ----------------
__global__ __launch_bounds__(256) void k_bucket(const int* __restrict__ esrc,
                                                const int* __restrict__ edst,
                                                int* __restrict__ cnt,
                                                int* __restrict__ bucket, int E) {
    int e = blockIdx.x * 256 + threadIdx.x;
    if (e >= E) return;
    int d = edst[e];
    int slot = atomicAdd(cnt + d, 1);
    if (slot < BCAP) bucket[(size_t)d * BCAP + slot] = esrc[e];
}

// ---- fused layer1: [BN_prev+ReLU -> neighbor-sum gather -> GEMM1 -> stats1] ----
// Gather v2: wave-per-row, all 16 bucket rows preloaded into regs (16 loads in
// flight at wave start), self term = virtual slot 0, 8 slots (2 loads/lane) per
// inner iteration, clamp-don't-guard (no divergence, poison-safe).
template<bool FIRST>
__global__ __launch_bounds__(256) void k_layer1(const void* __restrict__ hin,
                                                const float* __restrict__ stp,
                                                const float* __restrict__ gp,
                                                const float* __restrict__ bep,
                                                const int* __restrict__ cnt,
                                                const int* __restrict__ bucket,
                                                const unsigned short* __restrict__ Wt,
                                                const float* __restrict__ bias,
                                                unsigned short* __restrict__ Out,
                                                float* __restrict__ stats, int N) {
    __shared__ float ssS[2 * HID];
    __shared__ float csum[HID], csq[HID];
    __shared__ unsigned short As[64 * HID];   // bf16 agg rows, XOR-swizzled
    const int t = threadIdx.x;
    if (t < HID) { csum[t] = 0.f; csq[t] = 0.f; }
    if constexpr (!FIRST) compute_ss(stp, gp, bep, ssS, N, t);
    __syncthreads();

    const int wave = t >> 6, lane = t & 63;
    char* Abase = (char*)As + wave * 16 * 256;   // this wave's 16 rows
    const int r0w = blockIdx.x * 64 + wave * 16;

    // ---- preload degree + all bucket rows (clamped addresses, no guards) ----
    int cnt16 = 0;
    if (lane < 16) cnt16 = cnt[uminc(r0w + lane, N - 1)];
    int sb_all[16];
#pragma unroll
    for (int rr = 0; rr < 16; ++rr)
        sb_all[rr] = bucket[(size_t)uminc(r0w + rr, N - 1) * BCAP + lane];

    // ------------------ phase 1: gather ------------------
    if constexpr (!FIRST) {
        const int cg  = lane & 15;   // col group: cols cg*8 .. cg*8+7
        const int grp = lane >> 4;   // slot group 0..3
        float sc[8], sh[8];
#pragma unroll
        for (int q = 0; q < 8; ++q) { sc[q] = ssS[cg * 8 + q]; sh[q] = ssS[HID + cg * 8 + q]; }
        const unsigned short* H = (const unsigned short*)hin;
#pragma unroll 2
        for (int rr = 0; rr < 16; ++rr) {
            const int rowc = uminc(r0w + rr, N - 1);
            const int deg = min(__shfl(cnt16, rr), BCAP);
            const int T = deg + 1;            // virtual slot 0 = self
            float a[8];
#pragma unroll
            for (int q = 0; q < 8; ++q) a[q] = 0.f;
            const int nIt = (T + 7) >> 3;
            for (int it = 0; it < nIt; ++it) {
                const int s0 = it * 8 + grp;
                const int s1 = it * 8 + 4 + grp;
                const int n0 = __shfl(sb_all[rr], (s0 - 1) & 63);
                const int n1 = __shfl(sb_all[rr], (s1 - 1) & 63);
                const int src0 = (s0 == 0) ? rowc : uminc(n0, N - 1);
                const int src1 = uminc(n1, N - 1);
                const float m0 = (s0 < T) ? 1.f : 0.f;
                const float m1 = (s1 < T) ? 1.f : 0.f;
                const ushort8v v0 = *(const ushort8v*)(H + (size_t)src0 * HID + cg * 8);
                const ushort8v v1 = *(const ushort8v*)(H + (size_t)src1 * HID + cg * 8);
#pragma unroll
                for (int q = 0; q < 8; ++q)
                    a[q] = fmaf(fmaxf(fmaf(b2f(v0[q]), sc[q], sh[q]), 0.f), m0, a[q]);
#pragma unroll
                for (int q = 0; q < 8; ++q)
                    a[q] = fmaf(fmaxf(fmaf(b2f(v1[q]), sc[q], sh[q]), 0.f), m1, a[q]);
            }
#pragma unroll
            for (int q = 0; q < 8; ++q) {
                a[q] += __shfl_xor(a[q], 16);
                a[q] += __shfl_xor(a[q], 32);
            }
            if (grp == 0) {
                ushort8v pk;
#pragma unroll
                for (int q = 0; q < 8; ++q) pk[q] = f2b(a[q]);
                const int byt = (rr * 256 + cg * 16) ^ ((rr & 7) << 4);
                *(ushort8v*)(Abase + byt) = pk;
            }
        }
    } else {
        const int cg  = lane & 31;   // col group: cols cg*4 .. cg*4+3 (fp32 rows)
        const int grp = lane >> 5;   // slot group 0..1
        const float* H = (const float*)hin;
#pragma unroll 2
        for (int rr = 0; rr < 16; ++rr) {
            const int rowc = uminc(r0w + rr, N - 1);
            const int deg = min(__shfl(cnt16, rr), BCAP);
            const int T = deg + 1;
            float a[4] = {0.f, 0.f, 0.f, 0.f};
            const int nIt = (T + 3) >> 2;
            for (int it = 0; it < nIt; ++it) {
                const int s0 = it * 4 + grp;
                const int s1 = it * 4 + 2 + grp;
                const int n0 = __shfl(sb_all[rr], (s0 - 1) & 63);
                const int n1 = __shfl(sb_all[rr], (s1 - 1) & 63);
                const int src0 = (s0 == 0) ? rowc : uminc(n0, N - 1);
                const int src1 = uminc(n1, N - 1);
                const float m0 = (s0 < T) ? 1.f : 0.f;
                const float m1 = (s1 < T) ? 1.f : 0.f;
                const float4v v0 = *(const float4v*)(H + (size_t)src0 * HID + cg * 4);
                const float4v v1 = *(const float4v*)(H + (size_t)src1 * HID + cg * 4);
#pragma unroll
                for (int q = 0; q < 4; ++q) a[q] = fmaf(v0[q], m0, a[q]);
#pragma unroll
                for (int q = 0; q < 4; ++q) a[q] = fmaf(v1[q], m1, a[q]);
            }
#pragma unroll
            for (int q = 0; q < 4; ++q) a[q] += __shfl_xor(a[q], 32);
            if (grp == 0) {
                ushort4v pk;
#pragma unroll
                for (int q = 0; q < 4; ++q) pk[q] = f2b(a[q]);
                const int byt = (rr * 256 + cg * 8) ^ ((rr & 7) << 4);
                *(ushort4v*)(Abase + byt) = pk;
            }
        }
    }

    // ------------------ phase 2: GEMM from LDS ------------------
    const int lr = lane & 15, lk = lane >> 4;
    const int r0 = r0w;
    short8v af[4];
#pragma unroll
    for (int kb = 0; kb < 4; ++kb) {
        const int byt = (lr * 256 + kb * 64 + lk * 16) ^ ((lr & 7) << 4);
        af[kb] = *(const short8v*)(Abase + byt);
    }
    float4v acc[8];
#pragma unroll
    for (int ct = 0; ct < 8; ++ct) {
        float4v c = {0.f, 0.f, 0.f, 0.f};
        const unsigned short* bw = Wt + (size_t)(ct * 16 + lr) * HID + lk * 8;
#pragma unroll
        for (int kb = 0; kb < 4; ++kb) {
            short8v bf = *reinterpret_cast<const short8v*>(bw + kb * 32);
            c = __builtin_amdgcn_mfma_f32_16x16x32_bf16(af[kb], bf, c, 0, 0, 0);
        }
        acc[ct] = c;
    }

#pragma unroll
    for (int ct = 0; ct < 8; ++ct) {
        const int col = ct * 16 + lr;
        const float b = bias[col];
        float s = 0.f, q = 0.f;
#pragma unroll
        for (int j = 0; j < 4; ++j) {
            const int row = r0 + lk * 4 + j;
            if (row < N) {
                const float o = acc[ct][j] + b;
                Out[(size_t)row * HID + col] = f2b(o);
                s += o; q += o * o;
            }
        }
        s += __shfl_xor(s, 16); s += __shfl_xor(s, 32);
        q += __shfl_xor(q, 16); q += __shfl_xor(q, 32);
        if (lk == 0) { atomicAdd(&csum[col], s); atomicAdd(&csq[col], q); }
    }
    __syncthreads();
    if (t < HID) {
        atomicAdd(stats + t, csum[t]);
        atomicAdd(stats + HID + t, csq[t]);
    }
}

// ---- layer2: [fin1 inline -> BN1+ReLU on p1 -> GEMM2 -> p2 bf16, stats2] -------
__global__ __launch_bounds__(256) void k_layer2(const unsigned short* __restrict__ A,
                                                const float* __restrict__ st_in,
                                                const float* __restrict__ g_in,
                                                const float* __restrict__ be_in,
                                                const unsigned short* __restrict__ Wt,
                                                const float* __restrict__ bias,
                                                unsigned short* __restrict__ Out,
                                                float* __restrict__ stats, int M) {
    __shared__ float ssS[2 * HID];
    __shared__ float csum[HID], csq[HID];
    const int t = threadIdx.x;
    if (t < HID) { csum[t] = 0.f; csq[t] = 0.f; }
    compute_ss(st_in, g_in, be_in, ssS, M, t);
    __syncthreads();

    const int wave = t >> 6, lane = t & 63;
    const int lr = lane & 15, lk = lane >> 4;
    const int r0 = blockIdx.x * 64 + wave * 16;
    const int arow = r0 + lr;
    const bool rowok = arow < M;

    short8v af[4];
    const unsigned short* ap = A + (size_t)arow * HID + lk * 8;
#pragma unroll
    for (int kb = 0; kb < 4; ++kb) {
        ushort8v raw;
        if (rowok) raw = *reinterpret_cast<const ushort8v*>(ap + kb * 32);
        else       raw = (ushort8v)(unsigned short)0;
        const int k0 = kb * 32 + lk * 8;
        const float4v sc0 = *(const float4v*)&ssS[k0];
        const float4v sc1 = *(const float4v*)&ssS[k0 + 4];
        const float4v sh0 = *(const float4v*)&ssS[HID + k0];
        const float4v sh1 = *(const float4v*)&ssS[HID + k0 + 4];
        ushort8v pk;
#pragma unroll
        for (int j = 0; j < 4; ++j) {
            pk[j]     = f2b(fmaxf(fmaf(b2f(raw[j]),     sc0[j], sh0[j]), 0.f));
            pk[j + 4] = f2b(fmaxf(fmaf(b2f(raw[j + 4]), sc1[j], sh1[j]), 0.f));
        }
        af[kb] = *reinterpret_cast<short8v*>(&pk);
    }

    float4v acc[8];
#pragma unroll
    for (int ct = 0; ct < 8; ++ct) {
        float4v c = {0.f, 0.f, 0.f, 0.f};
        const unsigned short* bw = Wt + (size_t)(ct * 16 + lr) * HID + lk * 8;
#pragma unroll
        for (int kb = 0; kb < 4; ++kb) {
            short8v bf = *reinterpret_cast<const short8v*>(bw + kb * 32);
            c = __builtin_amdgcn_mfma_f32_16x16x32_bf16(af[kb], bf, c, 0, 0, 0);
        }
        acc[ct] = c;
    }

#pragma unroll
    for (int ct = 0; ct < 8; ++ct) {
        const int col = ct * 16 + lr;
        const float b = bias[col];
        float s = 0.f, q = 0.f;
#pragma unroll
        for (int j = 0; j < 4; ++j) {
            const int row = r0 + lk * 4 + j;
            if (row < M) {
                const float o = acc[ct][j] + b;
                Out[(size_t)row * HID + col] = f2b(o);
                s += o; q += o * o;
            }
        }
        s += __shfl_xor(s, 16); s += __shfl_xor(s, 32);
        q += __shfl_xor(q, 16); q += __shfl_xor(q, 32);
        if (lk == 0) { atomicAdd(&csum[col], s); atomicAdd(&csq[col], q); }
    }
    __syncthreads();
    if (t < HID) {
        atomicAdd(stats + t, csum[t]);
        atomicAdd(stats + HID + t, csq[t]);
    }
}

// ---- pool: [fin2 inline -> BN2+ReLU -> per-graph add-pool], grid (256, 8) ------
__global__ __launch_bounds__(HID) void k_pool(const unsigned short* __restrict__ p2,
                                              const float* __restrict__ st,
                                              const float* __restrict__ g,
                                              const float* __restrict__ be,
                                              const int* __restrict__ batch,
                                              int N, float* __restrict__ feats, int it) {
    __shared__ float ssS[2 * HID];
    const int t = threadIdx.x;
    compute_ss(st, g, be, ssS, N, t);
    __syncthreads();
    const int gph = blockIdx.x;
    int a = 0, b = N;
    while (a < b) { int m = (a + b) >> 1; if (batch[m] < gph) a = m + 1; else b = m; }
    const int lo = a;
    b = N;
    while (a < b) { int m = (a + b) >> 1; if (batch[m] < gph + 1) a = m + 1; else b = m; }
    const int hi = a;
    const int len = hi - lo;
    const int r0 = lo + (int)(((long long)len * blockIdx.y) >> 3);
    const int r1 = lo + (int)(((long long)len * (blockIdx.y + 1)) >> 3);
    const float sc = ssS[t], sh = ssS[HID + t];
    float acc = 0.f;
    for (int r = r0; r < r1; ++r)
        acc += fmaxf(fmaf(b2f(p2[(size_t)r * HID + t]), sc, sh), 0.f);
    if (r1 > r0)
        atomicAdd(&feats[(size_t)gph * (KIT * HID) + it * HID + t], acc);
}

// ---------------- weight prep: Wt[mat][n][k] = bf16(W[mat][k][n]) ---------------
__global__ __launch_bounds__(256) void k_wprep(const float* __restrict__ W,
                                               unsigned short* __restrict__ Wt) {
    int m = blockIdx.x;
    const float* w = W + (size_t)m * HID * HID;
    unsigned short* wt = Wt + (size_t)m * HID * HID;
    for (int idx = threadIdx.x; idx < HID * HID; idx += 256) {
        int k = idx >> 7, n = idx & 127;
        wt[n * HID + k] = f2b(w[k * HID + n]);
    }
}

// ---------------- head layer 1: z1 = relu(feats @ Wh1 + bh1)  [256,640] ---------
__global__ __launch_bounds__(KIT * HID) void k_head1(const float* __restrict__ feats,
                                                     const float* __restrict__ Wh1,
                                                     const float* __restrict__ bh1,
                                                     float* __restrict__ z1) {
    __shared__ float fr[KIT * HID];
    int r = blockIdx.x;
    int c = threadIdx.x;
    fr[c] = feats[r * (KIT * HID) + c];
    __syncthreads();
    float acc = bh1[c];
    for (int k = 0; k < KIT * HID; ++k) acc = fmaf(fr[k], Wh1[k * (KIT * HID) + c], acc);
    z1[r * (KIT * HID) + c] = fmaxf(acc, 0.f);
}

// ---------------- head layer 2: out = z1 @ Wh2 + bh2  [256,10] ------------------
__global__ __launch_bounds__(64) void k_head2(const float* __restrict__ z1,
                                              const float* __restrict__ Wh2,
                                              const float* __restrict__ bh2,
                                              float* __restrict__ out, int total) {
    int gid = blockIdx.x * 64 + threadIdx.x;
    if (gid >= total) return;
    int r = gid / 10, c = gid % 10;
    float acc = bh2[c];
    for (int k = 0; k < KIT * HID; ++k) acc = fmaf(z1[r * (KIT * HID) + k], Wh2[k * 10 + c], acc);
    out[gid] = acc;
}

extern "C" void kernel_launch(void* const* d_in, const int* in_sizes, int n_in,
                              void* d_out, int out_size, void* d_ws, size_t ws_size,
                              hipStream_t stream) {
    const float* X   = (const float*)d_in[0];
    const float* W1  = (const float*)d_in[1];
    const float* b1  = (const float*)d_in[2];
    const float* g1  = (const float*)d_in[3];
    const float* be1 = (const float*)d_in[4];
    const float* W2  = (const float*)d_in[5];
    const float* b2  = (const float*)d_in[6];
    const float* g2  = (const float*)d_in[7];
    const float* be2 = (const float*)d_in[8];
    const float* Wh1 = (const float*)d_in[9];
    const float* bh1 = (const float*)d_in[10];
    const float* Wh2 = (const float*)d_in[11];
    const float* bh2 = (const float*)d_in[12];
    const int* esrc  = (const int*)d_in[13];
    const int* edst  = (const int*)d_in[14];
    const int* batch = (const int*)d_in[15];
    float* out = (float*)d_out;

    const int N = in_sizes[0] / HID;
    const int E = in_sizes[13];

    char* w = (char*)d_ws;
    size_t off = 0;
    auto alloc = [&](size_t bytes) {
        void* p = w + off;
        off += (bytes + 255) & ~(size_t)255;
        return p;
    };
    unsigned short* p1b  = (unsigned short*)alloc((size_t)N * HID * 2);
    unsigned short* p2b  = (unsigned short*)alloc((size_t)N * HID * 2);
    unsigned short* Wt1  = (unsigned short*)alloc((size_t)KIT * HID * HID * 2);
    unsigned short* Wt2  = (unsigned short*)alloc((size_t)KIT * HID * HID * 2);
    float* feats  = (float*)alloc((size_t)NGRAPH * KIT * HID * 4);
    float* z1     = (float*)alloc((size_t)NGRAPH * KIT * HID * 4);
    float* stats  = (float*)alloc((size_t)2 * KIT * 2 * HID * 4);
    int*   cnt    = (int*)alloc((size_t)N * 4);
    int*   bucket = (int*)alloc((size_t)N * BCAP * 4);

    hipMemsetAsync(cnt, 0, (size_t)N * 4, stream);
    hipMemsetAsync(stats, 0, (size_t)2 * KIT * 2 * HID * 4, stream);
    hipMemsetAsync(feats, 0, (size_t)NGRAPH * KIT * HID * 4, stream);

    k_bucket<<<(E + 255) / 256, 256, 0, stream>>>(esrc, edst, cnt, bucket, E);
    k_wprep<<<KIT, 256, 0, stream>>>(W1, Wt1);
    k_wprep<<<KIT, 256, 0, stream>>>(W2, Wt2);

    const int gemmGrid = (N + 63) / 64;
    for (int i = 0; i < KIT; ++i) {
        float* st1 = stats + (size_t)(2 * i) * 256;
        float* st2 = stats + (size_t)(2 * i + 1) * 256;

        if (i == 0) {
            k_layer1<true><<<gemmGrid, 256, 0, stream>>>(
                X, nullptr, nullptr, nullptr, cnt, bucket,
                Wt1, b1, p1b, st1, N);
        } else {
            const float* stp = stats + (size_t)(2 * (i - 1) + 1) * 256;
            k_layer1<false><<<gemmGrid, 256, 0, stream>>>(
                p2b, stp, g2 + (i - 1) * HID, be2 + (i - 1) * HID, cnt, bucket,
                Wt1 + (size_t)i * HID * HID, b1 + i * HID, p1b, st1, N);
        }
        k_layer2<<<gemmGrid, 256, 0, stream>>>(
            p1b, st1, g1 + i * HID, be1 + i * HID,
            Wt2 + (size_t)i * HID * HID, b2 + i * HID, p2b, st2, N);
        k_pool<<<dim3(NGRAPH, 8), HID, 0, stream>>>(
            p2b, st2, g2 + i * HID, be2 + i * HID, batch, N, feats, i);
    }
    k_head1<<<NGRAPH, KIT * HID, 0, stream>>>(feats, Wh1, bh1, z1);
    k_head2<<<(NGRAPH * 10 + 63) / 64, 64, 0, stream>>>(z1, Wh2, bh2, out, NGRAPH * 10);
}

// Round 6
// 1273.870 us; speedup vs baseline: 1.8716x; 1.0149x over previous
//
#include <hip/hip_runtime.h>
#include <cstddef>

#define HID 128
#define NGRAPH 256
#define KIT 5
#define BCAP 64
#define BN_EPS 1e-5f

typedef __attribute__((ext_vector_type(8))) short  short8v;
typedef __attribute__((ext_vector_type(8))) unsigned short ushort8v;
typedef __attribute__((ext_vector_type(4))) unsigned short ushort4v;
typedef __attribute__((ext_vector_type(4))) float  float4v;

__device__ __forceinline__ unsigned short f2b(float f) {
    unsigned int u = __float_as_uint(f);
    u = (u + 0x7FFFu + ((u >> 16) & 1u)) >> 16;
    return (unsigned short)u;
}
__device__ __forceinline__ float b2f(unsigned short b) {
    return __uint_as_float(((unsigned int)b) << 16);
}
__device__ __forceinline__ int uminc(int v, int hi) {   // clamp via unsigned min
    return (int)min((unsigned)v, (unsigned)hi);
}

// BN finalize, done redundantly per block: ssS[c]=scale, ssS[128+c]=shift
__device__ __forceinline__ void compute_ss(const float* __restrict__ st,
                                           const float* __restrict__ g,
                                           const float* __restrict__ be,
                                           float* ssS, int M, int t) {
    if (t < HID) {
        float invM = 1.f / (float)M;
        float m = st[t] * invM;
        float v = fmaxf(st[HID + t] * invM - m * m, 0.f);
        float sc = rsqrtf(v + BN_EPS) * g[t];
        ssS[t] = sc;
        ssS[HID + t] = fmaf(-m, sc, be[t]);
    }
}

// ---------------- bucket build (CSR-lite, capacity BCAP per node) ----------------
__global__ __launch_bounds__(256) void k_bucket(const int* __restrict__ esrc,
                                                const int* __restrict__ edst,
                                                int* __restrict__ cnt,
                                                int* __restrict__ bucket, int E) {
    int e = blockIdx.x * 256 + threadIdx.x;
    if (e >= E) return;
    int d = edst[e];
    int slot = atomicAdd(cnt + d, 1);
    if (slot < BCAP) bucket[(size_t)d * BCAP + slot] = esrc[e];
}

// ---------------- X -> bf16 pre-convert ----------------
__global__ __launch_bounds__(256) void k_xprep(const float* __restrict__ X,
                                               unsigned short* __restrict__ Xb, int n8) {
    int i = blockIdx.x * 256 + threadIdx.x;
    if (i >= n8) return;
    const float4v v0 = ((const float4v*)X)[i * 2];
    const float4v v1 = ((const float4v*)X)[i * 2 + 1];
    ushort8v pk;
#pragma unroll
    for (int q = 0; q < 4; ++q) { pk[q] = f2b(v0[q]); pk[q + 4] = f2b(v1[q]); }
    ((ushort8v*)Xb)[i] = pk;
}

// ---- fused layer1: [BN_prev+ReLU -> neighbor-sum gather -> GEMM1 -> stats1] ----
// Gather v3: wave-per-row, bucket rows preloaded, 16 slots (4 loads/lane) per
// inner iteration (nIt=1 for deg<=15), masked slots load rowc (L2-hot).
// HAS_BN=false: identity transform (first layer, bf16 X).
template<bool HAS_BN>
__global__ __launch_bounds__(256) void k_layer1(const unsigned short* __restrict__ H,
                                                const float* __restrict__ stp,
                                                const float* __restrict__ gp,
                                                const float* __restrict__ bep,
                                                const int* __restrict__ cnt,
                                                const int* __restrict__ bucket,
                                                const unsigned short* __restrict__ Wt,
                                                const float* __restrict__ bias,
                                                unsigned short* __restrict__ Out,
                                                float* __restrict__ stats, int N) {
    __shared__ float ssS[2 * HID];
    __shared__ float csum[HID], csq[HID];
    __shared__ unsigned short As[64 * HID];   // bf16 agg rows, XOR-swizzled
    const int t = threadIdx.x;
    if (t < HID) { csum[t] = 0.f; csq[t] = 0.f; }
    if constexpr (HAS_BN) compute_ss(stp, gp, bep, ssS, N, t);
    __syncthreads();

    const int wave = t >> 6, lane = t & 63;
    char* Abase = (char*)As + wave * 16 * 256;   // this wave's 16 rows
    const int r0w = blockIdx.x * 64 + wave * 16;

    // ---- preload degree + all bucket rows (clamped addresses, no guards) ----
    int cnt16 = 0;
    if (lane < 16) cnt16 = cnt[uminc(r0w + lane, N - 1)];
    int sb_all[16];
#pragma unroll
    for (int rr = 0; rr < 16; ++rr)
        sb_all[rr] = bucket[(size_t)uminc(r0w + rr, N - 1) * BCAP + lane];

    // ------------------ phase 1: gather ------------------
    {
        const int cg  = lane & 15;   // col group: cols cg*8 .. cg*8+7
        const int grp = lane >> 4;   // slot group 0..3
        float sc[8], sh[8];
        if constexpr (HAS_BN) {
#pragma unroll
            for (int q = 0; q < 8; ++q) { sc[q] = ssS[cg * 8 + q]; sh[q] = ssS[HID + cg * 8 + q]; }
        }
#pragma unroll 2
        for (int rr = 0; rr < 16; ++rr) {
            const int rowc = uminc(r0w + rr, N - 1);
            const int deg = min(__shfl(cnt16, rr), BCAP);
            const int T = deg + 1;            // virtual slot 0 = self
            float a[8];
#pragma unroll
            for (int q = 0; q < 8; ++q) a[q] = 0.f;
            const int nIt = (T + 15) >> 4;
            for (int it = 0; it < nIt; ++it) {
                const int base = it * 16 + grp;
                float m[4];
                ushort8v v[4];
#pragma unroll
                for (int j = 0; j < 4; ++j) {
                    const int s = base + j * 4;
                    const int n = __shfl(sb_all[rr], (s - 1) & 63);
                    const bool inb = (s < T);
                    const bool use_n = inb && (s != 0);
                    const int src = use_n ? uminc(n, N - 1) : rowc;
                    m[j] = inb ? 1.f : 0.f;
                    v[j] = *(const ushort8v*)(H + (size_t)src * HID + cg * 8);
                }
#pragma unroll
                for (int j = 0; j < 4; ++j) {
#pragma unroll
                    for (int q = 0; q < 8; ++q) {
                        float x = b2f(v[j][q]);
                        if constexpr (HAS_BN) x = fmaxf(fmaf(x, sc[q], sh[q]), 0.f);
                        a[q] = fmaf(x, m[j], a[q]);
                    }
                }
            }
#pragma unroll
            for (int q = 0; q < 8; ++q) {
                a[q] += __shfl_xor(a[q], 16);
                a[q] += __shfl_xor(a[q], 32);
            }
            if (grp == 0) {
                ushort8v pk;
#pragma unroll
                for (int q = 0; q < 8; ++q) pk[q] = f2b(a[q]);
                const int byt = (rr * 256 + cg * 16) ^ ((rr & 7) << 4);
                *(ushort8v*)(Abase + byt) = pk;
            }
        }
    }

    // ------------------ phase 2: GEMM from LDS ------------------
    const int lr = lane & 15, lk = lane >> 4;
    const int r0 = r0w;
    short8v af[4];
#pragma unroll
    for (int kb = 0; kb < 4; ++kb) {
        const int byt = (lr * 256 + kb * 64 + lk * 16) ^ ((lr & 7) << 4);
        af[kb] = *(const short8v*)(Abase + byt);
    }
    float4v acc[8];
#pragma unroll
    for (int ct = 0; ct < 8; ++ct) {
        float4v c = {0.f, 0.f, 0.f, 0.f};
        const unsigned short* bw = Wt + (size_t)(ct * 16 + lr) * HID + lk * 8;
#pragma unroll
        for (int kb = 0; kb < 4; ++kb) {
            short8v bf = *reinterpret_cast<const short8v*>(bw + kb * 32);
            c = __builtin_amdgcn_mfma_f32_16x16x32_bf16(af[kb], bf, c, 0, 0, 0);
        }
        acc[ct] = c;
    }

#pragma unroll
    for (int ct = 0; ct < 8; ++ct) {
        const int col = ct * 16 + lr;
        const float b = bias[col];
        float s = 0.f, q = 0.f;
#pragma unroll
        for (int j = 0; j < 4; ++j) {
            const int row = r0 + lk * 4 + j;
            if (row < N) {
                const float o = acc[ct][j] + b;
                Out[(size_t)row * HID + col] = f2b(o);
                s += o; q += o * o;
            }
        }
        s += __shfl_xor(s, 16); s += __shfl_xor(s, 32);
        q += __shfl_xor(q, 16); q += __shfl_xor(q, 32);
        if (lk == 0) { atomicAdd(&csum[col], s); atomicAdd(&csq[col], q); }
    }
    __syncthreads();
    if (t < HID) {
        atomicAdd(stats + t, csum[t]);
        atomicAdd(stats + HID + t, csq[t]);
    }
}

// ---- layer2: [fin1 inline -> BN1+ReLU on p1 -> GEMM2 -> p2 bf16, stats2] -------
__global__ __launch_bounds__(256) void k_layer2(const unsigned short* __restrict__ A,
                                                const float* __restrict__ st_in,
                                                const float* __restrict__ g_in,
                                                const float* __restrict__ be_in,
                                                const unsigned short* __restrict__ Wt,
                                                const float* __restrict__ bias,
                                                unsigned short* __restrict__ Out,
                                                float* __restrict__ stats, int M) {
    __shared__ float ssS[2 * HID];
    __shared__ float csum[HID], csq[HID];
    const int t = threadIdx.x;
    if (t < HID) { csum[t] = 0.f; csq[t] = 0.f; }
    compute_ss(st_in, g_in, be_in, ssS, M, t);
    __syncthreads();

    const int wave = t >> 6, lane = t & 63;
    const int lr = lane & 15, lk = lane >> 4;
    const int r0 = blockIdx.x * 64 + wave * 16;
    const int arow = r0 + lr;
    const bool rowok = arow < M;

    short8v af[4];
    const unsigned short* ap = A + (size_t)arow * HID + lk * 8;
#pragma unroll
    for (int kb = 0; kb < 4; ++kb) {
        ushort8v raw;
        if (rowok) raw = *reinterpret_cast<const ushort8v*>(ap + kb * 32);
        else       raw = (ushort8v)(unsigned short)0;
        const int k0 = kb * 32 + lk * 8;
        const float4v sc0 = *(const float4v*)&ssS[k0];
        const float4v sc1 = *(const float4v*)&ssS[k0 + 4];
        const float4v sh0 = *(const float4v*)&ssS[HID + k0];
        const float4v sh1 = *(const float4v*)&ssS[HID + k0 + 4];
        ushort8v pk;
#pragma unroll
        for (int j = 0; j < 4; ++j) {
            pk[j]     = f2b(fmaxf(fmaf(b2f(raw[j]),     sc0[j], sh0[j]), 0.f));
            pk[j + 4] = f2b(fmaxf(fmaf(b2f(raw[j + 4]), sc1[j], sh1[j]), 0.f));
        }
        af[kb] = *reinterpret_cast<short8v*>(&pk);
    }

    float4v acc[8];
#pragma unroll
    for (int ct = 0; ct < 8; ++ct) {
        float4v c = {0.f, 0.f, 0.f, 0.f};
        const unsigned short* bw = Wt + (size_t)(ct * 16 + lr) * HID + lk * 8;
#pragma unroll
        for (int kb = 0; kb < 4; ++kb) {
            short8v bf = *reinterpret_cast<const short8v*>(bw + kb * 32);
            c = __builtin_amdgcn_mfma_f32_16x16x32_bf16(af[kb], bf, c, 0, 0, 0);
        }
        acc[ct] = c;
    }

#pragma unroll
    for (int ct = 0; ct < 8; ++ct) {
        const int col = ct * 16 + lr;
        const float b = bias[col];
        float s = 0.f, q = 0.f;
#pragma unroll
        for (int j = 0; j < 4; ++j) {
            const int row = r0 + lk * 4 + j;
            if (row < M) {
                const float o = acc[ct][j] + b;
                Out[(size_t)row * HID + col] = f2b(o);
                s += o; q += o * o;
            }
        }
        s += __shfl_xor(s, 16); s += __shfl_xor(s, 32);
        q += __shfl_xor(q, 16); q += __shfl_xor(q, 32);
        if (lk == 0) { atomicAdd(&csum[col], s); atomicAdd(&csq[col], q); }
    }
    __syncthreads();
    if (t < HID) {
        atomicAdd(stats + t, csum[t]);
        atomicAdd(stats + HID + t, csq[t]);
    }
}

// ---- pool: [fin2 inline -> BN2+ReLU -> per-graph add-pool], grid (256, 8) ------
__global__ __launch_bounds__(HID) void k_pool(const unsigned short* __restrict__ p2,
                                              const float* __restrict__ st,
                                              const float* __restrict__ g,
                                              const float* __restrict__ be,
                                              const int* __restrict__ batch,
                                              int N, float* __restrict__ feats, int it) {
    __shared__ float ssS[2 * HID];
    const int t = threadIdx.x;
    compute_ss(st, g, be, ssS, N, t);
    __syncthreads();
    const int gph = blockIdx.x;
    int a = 0, b = N;
    while (a < b) { int m = (a + b) >> 1; if (batch[m] < gph) a = m + 1; else b = m; }
    const int lo = a;
    b = N;
    while (a < b) { int m = (a + b) >> 1; if (batch[m] < gph + 1) a = m + 1; else b = m; }
    const int hi = a;
    const int len = hi - lo;
    const int r0 = lo + (int)(((long long)len * blockIdx.y) >> 3);
    const int r1 = lo + (int)(((long long)len * (blockIdx.y + 1)) >> 3);
    const float sc = ssS[t], sh = ssS[HID + t];
    float acc = 0.f;
    for (int r = r0; r < r1; ++r)
        acc += fmaxf(fmaf(b2f(p2[(size_t)r * HID + t]), sc, sh), 0.f);
    if (r1 > r0)
        atomicAdd(&feats[(size_t)gph * (KIT * HID) + it * HID + t], acc);
}

// ---------------- weight prep: Wt[mat][n][k] = bf16(W[mat][k][n]) ---------------
__global__ __launch_bounds__(256) void k_wprep(const float* __restrict__ W,
                                               unsigned short* __restrict__ Wt) {
    int m = blockIdx.x;
    const float* w = W + (size_t)m * HID * HID;
    unsigned short* wt = Wt + (size_t)m * HID * HID;
    for (int idx = threadIdx.x; idx < HID * HID; idx += 256) {
        int k = idx >> 7, n = idx & 127;
        wt[n * HID + k] = f2b(w[k * HID + n]);
    }
}

// ---------------- head layer 1: z1 = relu(feats @ Wh1 + bh1)  [256,640] ---------
__global__ __launch_bounds__(KIT * HID) void k_head1(const float* __restrict__ feats,
                                                     const float* __restrict__ Wh1,
                                                     const float* __restrict__ bh1,
                                                     float* __restrict__ z1) {
    __shared__ float fr[KIT * HID];
    int r = blockIdx.x;
    int c = threadIdx.x;
    fr[c] = feats[r * (KIT * HID) + c];
    __syncthreads();
    float acc = bh1[c];
    for (int k = 0; k < KIT * HID; ++k) acc = fmaf(fr[k], Wh1[k * (KIT * HID) + c], acc);
    z1[r * (KIT * HID) + c] = fmaxf(acc, 0.f);
}

// ---------------- head layer 2: out = z1 @ Wh2 + bh2  [256,10] ------------------
__global__ __launch_bounds__(64) void k_head2(const float* __restrict__ z1,
                                              const float* __restrict__ Wh2,
                                              const float* __restrict__ bh2,
                                              float* __restrict__ out, int total) {
    int gid = blockIdx.x * 64 + threadIdx.x;
    if (gid >= total) return;
    int r = gid / 10, c = gid % 10;
    float acc = bh2[c];
    for (int k = 0; k < KIT * HID; ++k) acc = fmaf(z1[r * (KIT * HID) + k], Wh2[k * 10 + c], acc);
    out[gid] = acc;
}

extern "C" void kernel_launch(void* const* d_in, const int* in_sizes, int n_in,
                              void* d_out, int out_size, void* d_ws, size_t ws_size,
                              hipStream_t stream) {
    const float* X   = (const float*)d_in[0];
    const float* W1  = (const float*)d_in[1];
    const float* b1  = (const float*)d_in[2];
    const float* g1  = (const float*)d_in[3];
    const float* be1 = (const float*)d_in[4];
    const float* W2  = (const float*)d_in[5];
    const float* b2  = (const float*)d_in[6];
    const float* g2  = (const float*)d_in[7];
    const float* be2 = (const float*)d_in[8];
    const float* Wh1 = (const float*)d_in[9];
    const float* bh1 = (const float*)d_in[10];
    const float* Wh2 = (const float*)d_in[11];
    const float* bh2 = (const float*)d_in[12];
    const int* esrc  = (const int*)d_in[13];
    const int* edst  = (const int*)d_in[14];
    const int* batch = (const int*)d_in[15];
    float* out = (float*)d_out;

    const int N = in_sizes[0] / HID;
    const int E = in_sizes[13];

    char* w = (char*)d_ws;
    size_t off = 0;
    auto alloc = [&](size_t bytes) {
        void* p = w + off;
        off += (bytes + 255) & ~(size_t)255;
        return p;
    };
    unsigned short* Xb   = (unsigned short*)alloc((size_t)N * HID * 2);
    unsigned short* p1b  = (unsigned short*)alloc((size_t)N * HID * 2);
    unsigned short* p2b  = (unsigned short*)alloc((size_t)N * HID * 2);
    unsigned short* Wt1  = (unsigned short*)alloc((size_t)KIT * HID * HID * 2);
    unsigned short* Wt2  = (unsigned short*)alloc((size_t)KIT * HID * HID * 2);
    float* feats  = (float*)alloc((size_t)NGRAPH * KIT * HID * 4);
    float* z1     = (float*)alloc((size_t)NGRAPH * KIT * HID * 4);
    float* stats  = (float*)alloc((size_t)2 * KIT * 2 * HID * 4);
    int*   cnt    = (int*)alloc((size_t)N * 4);
    int*   bucket = (int*)alloc((size_t)N * BCAP * 4);

    hipMemsetAsync(cnt, 0, (size_t)N * 4, stream);
    hipMemsetAsync(stats, 0, (size_t)2 * KIT * 2 * HID * 4, stream);
    hipMemsetAsync(feats, 0, (size_t)NGRAPH * KIT * HID * 4, stream);

    k_bucket<<<(E + 255) / 256, 256, 0, stream>>>(esrc, edst, cnt, bucket, E);
    k_xprep<<<(N * (HID / 8) + 255) / 256, 256, 0, stream>>>(X, Xb, N * (HID / 8));
    k_wprep<<<KIT, 256, 0, stream>>>(W1, Wt1);
    k_wprep<<<KIT, 256, 0, stream>>>(W2, Wt2);

    const int gemmGrid = (N + 63) / 64;
    for (int i = 0; i < KIT; ++i) {
        float* st1 = stats + (size_t)(2 * i) * 256;
        float* st2 = stats + (size_t)(2 * i + 1) * 256;

        if (i == 0) {
            k_layer1<false><<<gemmGrid, 256, 0, stream>>>(
                Xb, nullptr, nullptr, nullptr, cnt, bucket,
                Wt1, b1, p1b, st1, N);
        } else {
            const float* stp = stats + (size_t)(2 * (i - 1) + 1) * 256;
            k_layer1<true><<<gemmGrid, 256, 0, stream>>>(
                p2b, stp, g2 + (i - 1) * HID, be2 + (i - 1) * HID, cnt, bucket,
                Wt1 + (size_t)i * HID * HID, b1 + i * HID, p1b, st1, N);
        }
        k_layer2<<<gemmGrid, 256, 0, stream>>>(
            p1b, st1, g1 + i * HID, be1 + i * HID,
            Wt2 + (size_t)i * HID * HID, b2 + i * HID, p2b, st2, N);
        k_pool<<<dim3(NGRAPH, 8), HID, 0, stream>>>(
            p2b, st2, g2 + i * HID, be2 + i * HID, batch, N, feats, i);
    }
    k_head1<<<NGRAPH, KIT * HID, 0, stream>>>(feats, Wh1, bh1, z1);
    k_head2<<<(NGRAPH * 10 + 63) / 64, 64, 0, stream>>>(z1, Wh2, bh2, out, NGRAPH * 10);
}

// Round 7
// 1253.941 us; speedup vs baseline: 1.9013x; 1.0159x over previous
//
#include <hip/hip_runtime.h>
#include <cstddef>

#define HID 128
#define NGRAPH 256
#define KIT 5
#define BCAP 64
#define BN_EPS 1e-5f

typedef __attribute__((ext_vector_type(8))) short  short8v;
typedef __attribute__((ext_vector_type(8))) unsigned short ushort8v;
typedef __attribute__((ext_vector_type(4))) float  float4v;

__device__ __forceinline__ unsigned short f2b(float f) {
    unsigned int u = __float_as_uint(f);
    u = (u + 0x7FFFu + ((u >> 16) & 1u)) >> 16;
    return (unsigned short)u;
}
__device__ __forceinline__ float b2f(unsigned short b) {
    return __uint_as_float(((unsigned int)b) << 16);
}
__device__ __forceinline__ int uminc(int v, int hi) {   // clamp via unsigned min
    return (int)min((unsigned)v, (unsigned)hi);
}

// BN finalize, done redundantly per block: ssS[c]=scale, ssS[128+c]=shift
__device__ __forceinline__ void compute_ss(const float* __restrict__ st,
                                           const float* __restrict__ g,
                                           const float* __restrict__ be,
                                           float* ssS, int M, int t) {
    if (t < HID) {
        float invM = 1.f / (float)M;
        float m = st[t] * invM;
        float v = fmaxf(st[HID + t] * invM - m * m, 0.f);
        float sc = rsqrtf(v + BN_EPS) * g[t];
        ssS[t] = sc;
        ssS[HID + t] = fmaf(-m, sc, be[t]);
    }
}

// ---------------- bucket build (CSR-lite, capacity BCAP per node) ----------------
__global__ __launch_bounds__(256) void k_bucket(const int* __restrict__ esrc,
                                                const int* __restrict__ edst,
                                                int* __restrict__ cnt,
                                                int* __restrict__ bucket, int E) {
    int e = blockIdx.x * 256 + threadIdx.x;
    if (e >= E) return;
    int d = edst[e];
    int slot = atomicAdd(cnt + d, 1);
    if (slot < BCAP) bucket[(size_t)d * BCAP + slot] = esrc[e];
}

// ---------------- X -> bf16 pre-convert ----------------
__global__ __launch_bounds__(256) void k_xprep(const float* __restrict__ X,
                                               unsigned short* __restrict__ Xb, int n8) {
    int i = blockIdx.x * 256 + threadIdx.x;
    if (i >= n8) return;
    const float4v v0 = ((const float4v*)X)[i * 2];
    const float4v v1 = ((const float4v*)X)[i * 2 + 1];
    ushort8v pk;
#pragma unroll
    for (int q = 0; q < 4; ++q) { pk[q] = f2b(v0[q]); pk[q + 4] = f2b(v1[q]); }
    ((ushort8v*)Xb)[i] = pk;
}

// ---- fused layer1: [pure-sum gather of pre-transformed h -> GEMM1 -> stats1] ----
// H has N+1 rows; row N is all zeros (masked-slot target). Gather is cvt+add only:
// wave-per-row, bucket rows preloaded, 16 slots (4 loads/lane) per inner iter.
__global__ __launch_bounds__(256) void k_layer1(const unsigned short* __restrict__ H,
                                                const int* __restrict__ cnt,
                                                const int* __restrict__ bucket,
                                                const unsigned short* __restrict__ Wt,
                                                const float* __restrict__ bias,
                                                unsigned short* __restrict__ Out,
                                                float* __restrict__ stats, int N) {
    __shared__ float csum[HID], csq[HID];
    __shared__ unsigned short As[64 * HID];   // bf16 agg rows, XOR-swizzled
    const int t = threadIdx.x;
    if (t < HID) { csum[t] = 0.f; csq[t] = 0.f; }
    __syncthreads();

    const int wave = t >> 6, lane = t & 63;
    char* Abase = (char*)As + wave * 16 * 256;   // this wave's 16 rows
    const int r0w = blockIdx.x * 64 + wave * 16;

    // ---- preload degree + all bucket rows (clamped addresses, no guards) ----
    int cnt16 = 0;
    if (lane < 16) cnt16 = cnt[uminc(r0w + lane, N - 1)];
    int sb_all[16];
#pragma unroll
    for (int rr = 0; rr < 16; ++rr)
        sb_all[rr] = bucket[(size_t)uminc(r0w + rr, N - 1) * BCAP + lane];

    // ------------------ phase 1: gather (pure adds) ------------------
    {
        const int cg  = lane & 15;   // col group: cols cg*8 .. cg*8+7
        const int grp = lane >> 4;   // slot group 0..3
#pragma unroll 2
        for (int rr = 0; rr < 16; ++rr) {
            const int rowc = uminc(r0w + rr, N - 1);
            const int deg = min(__shfl(cnt16, rr), BCAP);
            const int T = deg + 1;            // virtual slot 0 = self
            float a[8];
#pragma unroll
            for (int q = 0; q < 8; ++q) a[q] = 0.f;
            const int nIt = (T + 15) >> 4;
            for (int it = 0; it < nIt; ++it) {
                const int base = it * 16 + grp;
                ushort8v v[4];
#pragma unroll
                for (int j = 0; j < 4; ++j) {
                    const int s = base + j * 4;
                    const int n = __shfl(sb_all[rr], (s - 1) & 63);
                    int src = (s == 0) ? rowc : uminc(n, N - 1);
                    src = (s < T) ? src : N;          // zero row for masked slots
                    v[j] = *(const ushort8v*)(H + (size_t)src * HID + cg * 8);
                }
#pragma unroll
                for (int j = 0; j < 4; ++j)
#pragma unroll
                    for (int q = 0; q < 8; ++q)
                        a[q] += b2f(v[j][q]);
            }
#pragma unroll
            for (int q = 0; q < 8; ++q) {
                a[q] += __shfl_xor(a[q], 16);
                a[q] += __shfl_xor(a[q], 32);
            }
            if (grp == 0) {
                ushort8v pk;
#pragma unroll
                for (int q = 0; q < 8; ++q) pk[q] = f2b(a[q]);
                const int byt = (rr * 256 + cg * 16) ^ ((rr & 7) << 4);
                *(ushort8v*)(Abase + byt) = pk;
            }
        }
    }

    // ------------------ phase 2: GEMM from LDS ------------------
    const int lr = lane & 15, lk = lane >> 4;
    const int r0 = r0w;
    short8v af[4];
#pragma unroll
    for (int kb = 0; kb < 4; ++kb) {
        const int byt = (lr * 256 + kb * 64 + lk * 16) ^ ((lr & 7) << 4);
        af[kb] = *(const short8v*)(Abase + byt);
    }
    float4v acc[8];
#pragma unroll
    for (int ct = 0; ct < 8; ++ct) {
        float4v c = {0.f, 0.f, 0.f, 0.f};
        const unsigned short* bw = Wt + (size_t)(ct * 16 + lr) * HID + lk * 8;
#pragma unroll
        for (int kb = 0; kb < 4; ++kb) {
            short8v bf = *reinterpret_cast<const short8v*>(bw + kb * 32);
            c = __builtin_amdgcn_mfma_f32_16x16x32_bf16(af[kb], bf, c, 0, 0, 0);
        }
        acc[ct] = c;
    }

#pragma unroll
    for (int ct = 0; ct < 8; ++ct) {
        const int col = ct * 16 + lr;
        const float b = bias[col];
        float s = 0.f, q = 0.f;
#pragma unroll
        for (int j = 0; j < 4; ++j) {
            const int row = r0 + lk * 4 + j;
            if (row < N) {
                const float o = acc[ct][j] + b;
                Out[(size_t)row * HID + col] = f2b(o);
                s += o; q += o * o;
            }
        }
        s += __shfl_xor(s, 16); s += __shfl_xor(s, 32);
        q += __shfl_xor(q, 16); q += __shfl_xor(q, 32);
        if (lk == 0) { atomicAdd(&csum[col], s); atomicAdd(&csq[col], q); }
    }
    __syncthreads();
    if (t < HID) {
        atomicAdd(stats + t, csum[t]);
        atomicAdd(stats + HID + t, csq[t]);
    }
}

// ---- layer2: [fin1 inline -> BN1+ReLU on p1 -> GEMM2 -> p2 bf16, stats2] -------
__global__ __launch_bounds__(256) void k_layer2(const unsigned short* __restrict__ A,
                                                const float* __restrict__ st_in,
                                                const float* __restrict__ g_in,
                                                const float* __restrict__ be_in,
                                                const unsigned short* __restrict__ Wt,
                                                const float* __restrict__ bias,
                                                unsigned short* __restrict__ Out,
                                                float* __restrict__ stats, int M) {
    __shared__ float ssS[2 * HID];
    __shared__ float csum[HID], csq[HID];
    const int t = threadIdx.x;
    if (t < HID) { csum[t] = 0.f; csq[t] = 0.f; }
    compute_ss(st_in, g_in, be_in, ssS, M, t);
    __syncthreads();

    const int wave = t >> 6, lane = t & 63;
    const int lr = lane & 15, lk = lane >> 4;
    const int r0 = blockIdx.x * 64 + wave * 16;
    const int arow = r0 + lr;
    const bool rowok = arow < M;

    short8v af[4];
    const unsigned short* ap = A + (size_t)arow * HID + lk * 8;
#pragma unroll
    for (int kb = 0; kb < 4; ++kb) {
        ushort8v raw;
        if (rowok) raw = *reinterpret_cast<const ushort8v*>(ap + kb * 32);
        else       raw = (ushort8v)(unsigned short)0;
        const int k0 = kb * 32 + lk * 8;
        const float4v sc0 = *(const float4v*)&ssS[k0];
        const float4v sc1 = *(const float4v*)&ssS[k0 + 4];
        const float4v sh0 = *(const float4v*)&ssS[HID + k0];
        const float4v sh1 = *(const float4v*)&ssS[HID + k0 + 4];
        ushort8v pk;
#pragma unroll
        for (int j = 0; j < 4; ++j) {
            pk[j]     = f2b(fmaxf(fmaf(b2f(raw[j]),     sc0[j], sh0[j]), 0.f));
            pk[j + 4] = f2b(fmaxf(fmaf(b2f(raw[j + 4]), sc1[j], sh1[j]), 0.f));
        }
        af[kb] = *reinterpret_cast<short8v*>(&pk);
    }

    float4v acc[8];
#pragma unroll
    for (int ct = 0; ct < 8; ++ct) {
        float4v c = {0.f, 0.f, 0.f, 0.f};
        const unsigned short* bw = Wt + (size_t)(ct * 16 + lr) * HID + lk * 8;
#pragma unroll
        for (int kb = 0; kb < 4; ++kb) {
            short8v bf = *reinterpret_cast<const short8v*>(bw + kb * 32);
            c = __builtin_amdgcn_mfma_f32_16x16x32_bf16(af[kb], bf, c, 0, 0, 0);
        }
        acc[ct] = c;
    }

#pragma unroll
    for (int ct = 0; ct < 8; ++ct) {
        const int col = ct * 16 + lr;
        const float b = bias[col];
        float s = 0.f, q = 0.f;
#pragma unroll
        for (int j = 0; j < 4; ++j) {
            const int row = r0 + lk * 4 + j;
            if (row < M) {
                const float o = acc[ct][j] + b;
                Out[(size_t)row * HID + col] = f2b(o);
                s += o; q += o * o;
            }
        }
        s += __shfl_xor(s, 16); s += __shfl_xor(s, 32);
        q += __shfl_xor(q, 16); q += __shfl_xor(q, 32);
        if (lk == 0) { atomicAdd(&csum[col], s); atomicAdd(&csq[col], q); }
    }
    __syncthreads();
    if (t < HID) {
        atomicAdd(stats + t, csum[t]);
        atomicAdd(stats + HID + t, csq[t]);
    }
}

// ---- pool+writeback: [fin2 inline -> h=relu(bn(p2)) -> write h2b + add-pool] ----
__global__ __launch_bounds__(HID) void k_pool(const unsigned short* __restrict__ p2,
                                              const float* __restrict__ st,
                                              const float* __restrict__ g,
                                              const float* __restrict__ be,
                                              const int* __restrict__ batch,
                                              int N, float* __restrict__ feats, int it,
                                              unsigned short* __restrict__ hout) {
    __shared__ float ssS[2 * HID];
    const int t = threadIdx.x;
    compute_ss(st, g, be, ssS, N, t);
    __syncthreads();
    const int gph = blockIdx.x;
    int a = 0, b = N;
    while (a < b) { int m = (a + b) >> 1; if (batch[m] < gph) a = m + 1; else b = m; }
    const int lo = a;
    b = N;
    while (a < b) { int m = (a + b) >> 1; if (batch[m] < gph + 1) a = m + 1; else b = m; }
    const int hi = a;
    const int len = hi - lo;
    const int r0 = lo + (int)(((long long)len * blockIdx.y) >> 3);
    const int r1 = lo + (int)(((long long)len * (blockIdx.y + 1)) >> 3);
    const float sc = ssS[t], sh = ssS[HID + t];
    float acc = 0.f;
    for (int r = r0; r < r1; ++r) {
        const float hv = fmaxf(fmaf(b2f(p2[(size_t)r * HID + t]), sc, sh), 0.f);
        hout[(size_t)r * HID + t] = f2b(hv);
        acc += hv;
    }
    if (r1 > r0)
        atomicAdd(&feats[(size_t)gph * (KIT * HID) + it * HID + t], acc);
}

// ---------------- weight prep: Wt[mat][n][k] = bf16(W[mat][k][n]) ---------------
__global__ __launch_bounds__(256) void k_wprep(const float* __restrict__ W,
                                               unsigned short* __restrict__ Wt) {
    int m = blockIdx.x;
    const float* w = W + (size_t)m * HID * HID;
    unsigned short* wt = Wt + (size_t)m * HID * HID;
    for (int idx = threadIdx.x; idx < HID * HID; idx += 256) {
        int k = idx >> 7, n = idx & 127;
        wt[n * HID + k] = f2b(w[k * HID + n]);
    }
}

// ---------------- head layer 1: z1 = relu(feats @ Wh1 + bh1)  [256,640] ---------
__global__ __launch_bounds__(KIT * HID) void k_head1(const float* __restrict__ feats,
                                                     const float* __restrict__ Wh1,
                                                     const float* __restrict__ bh1,
                                                     float* __restrict__ z1) {
    __shared__ float fr[KIT * HID];
    int r = blockIdx.x;
    int c = threadIdx.x;
    fr[c] = feats[r * (KIT * HID) + c];
    __syncthreads();
    float acc = bh1[c];
    for (int k = 0; k < KIT * HID; ++k) acc = fmaf(fr[k], Wh1[k * (KIT * HID) + c], acc);
    z1[r * (KIT * HID) + c] = fmaxf(acc, 0.f);
}

// ---------------- head layer 2: out = z1 @ Wh2 + bh2  [256,10] ------------------
__global__ __launch_bounds__(64) void k_head2(const float* __restrict__ z1,
                                              const float* __restrict__ Wh2,
                                              const float* __restrict__ bh2,
                                              float* __restrict__ out, int total) {
    int gid = blockIdx.x * 64 + threadIdx.x;
    if (gid >= total) return;
    int r = gid / 10, c = gid % 10;
    float acc = bh2[c];
    for (int k = 0; k < KIT * HID; ++k) acc = fmaf(z1[r * (KIT * HID) + k], Wh2[k * 10 + c], acc);
    out[gid] = acc;
}

extern "C" void kernel_launch(void* const* d_in, const int* in_sizes, int n_in,
                              void* d_out, int out_size, void* d_ws, size_t ws_size,
                              hipStream_t stream) {
    const float* X   = (const float*)d_in[0];
    const float* W1  = (const float*)d_in[1];
    const float* b1  = (const float*)d_in[2];
    const float* g1  = (const float*)d_in[3];
    const float* be1 = (const float*)d_in[4];
    const float* W2  = (const float*)d_in[5];
    const float* b2  = (const float*)d_in[6];
    const float* g2  = (const float*)d_in[7];
    const float* be2 = (const float*)d_in[8];
    const float* Wh1 = (const float*)d_in[9];
    const float* bh1 = (const float*)d_in[10];
    const float* Wh2 = (const float*)d_in[11];
    const float* bh2 = (const float*)d_in[12];
    const int* esrc  = (const int*)d_in[13];
    const int* edst  = (const int*)d_in[14];
    const int* batch = (const int*)d_in[15];
    float* out = (float*)d_out;

    const int N = in_sizes[0] / HID;
    const int E = in_sizes[13];

    char* w = (char*)d_ws;
    size_t off = 0;
    auto alloc = [&](size_t bytes) {
        void* p = w + off;
        off += (bytes + 255) & ~(size_t)255;
        return p;
    };
    unsigned short* Xb   = (unsigned short*)alloc((size_t)(N + 1) * HID * 2);  // row N = 0
    unsigned short* h2b  = (unsigned short*)alloc((size_t)(N + 1) * HID * 2);  // row N = 0
    unsigned short* p1b  = (unsigned short*)alloc((size_t)N * HID * 2);
    unsigned short* p2b  = (unsigned short*)alloc((size_t)N * HID * 2);
    unsigned short* Wt1  = (unsigned short*)alloc((size_t)KIT * HID * HID * 2);
    unsigned short* Wt2  = (unsigned short*)alloc((size_t)KIT * HID * HID * 2);
    float* feats  = (float*)alloc((size_t)NGRAPH * KIT * HID * 4);
    float* z1     = (float*)alloc((size_t)NGRAPH * KIT * HID * 4);
    float* stats  = (float*)alloc((size_t)2 * KIT * 2 * HID * 4);
    int*   cnt    = (int*)alloc((size_t)N * 4);
    int*   bucket = (int*)alloc((size_t)N * BCAP * 4);

    hipMemsetAsync(cnt, 0, (size_t)N * 4, stream);
    hipMemsetAsync(stats, 0, (size_t)2 * KIT * 2 * HID * 4, stream);
    hipMemsetAsync(feats, 0, (size_t)NGRAPH * KIT * HID * 4, stream);
    hipMemsetAsync(Xb + (size_t)N * HID, 0, HID * 2, stream);
    hipMemsetAsync(h2b + (size_t)N * HID, 0, HID * 2, stream);

    k_bucket<<<(E + 255) / 256, 256, 0, stream>>>(esrc, edst, cnt, bucket, E);
    k_xprep<<<(N * (HID / 8) + 255) / 256, 256, 0, stream>>>(X, Xb, N * (HID / 8));
    k_wprep<<<KIT, 256, 0, stream>>>(W1, Wt1);
    k_wprep<<<KIT, 256, 0, stream>>>(W2, Wt2);

    const int gemmGrid = (N + 63) / 64;
    for (int i = 0; i < KIT; ++i) {
        float* st1 = stats + (size_t)(2 * i) * 256;
        float* st2 = stats + (size_t)(2 * i + 1) * 256;
        const unsigned short* hin = (i == 0) ? Xb : h2b;

        k_layer1<<<gemmGrid, 256, 0, stream>>>(
            hin, cnt, bucket, Wt1 + (size_t)i * HID * HID, b1 + i * HID, p1b, st1, N);
        k_layer2<<<gemmGrid, 256, 0, stream>>>(
            p1b, st1, g1 + i * HID, be1 + i * HID,
            Wt2 + (size_t)i * HID * HID, b2 + i * HID, p2b, st2, N);
        k_pool<<<dim3(NGRAPH, 8), HID, 0, stream>>>(
            p2b, st2, g2 + i * HID, be2 + i * HID, batch, N, feats, i, h2b);
    }
    k_head1<<<NGRAPH, KIT * HID, 0, stream>>>(feats, Wh1, bh1, z1);
    k_head2<<<(NGRAPH * 10 + 63) / 64, 64, 0, stream>>>(z1, Wh2, bh2, out, NGRAPH * 10);
}